// Round 2
// baseline (6137.735 us; speedup 1.0000x reference)
//
#include <hip/hip_runtime.h>
#include <hip/hip_bf16.h>

// ---------------------------------------------------------------------------
// SurpriseKimiDeltaAttention  (B=2, T=4096, H=2048, NH=16, DK=DV=128, CONV=4)
// Per-batch pipeline (b = 0,1) to keep workspace under ~189 MB:
//  1. cast weights (once) + x(b) to bf16
//  2. GEMM qkv(b) = x(b) @ [Wq;Wk;Wv]^T        (bf16 MFMA)
//  3. fused conv+silu + surprise stats + MLPs -> packed records P:
//     per (h,t): kn[128]|qn*scale[128]|v[128]|g[128] bf16 + beta f32
//  4. sequential delta-rule scan over t (parallel over h x v-col chunks)
//  5. gate GEMMs, RMS-norm*sigmoid gate, output GEMM -> d_out
// ---------------------------------------------------------------------------

typedef __attribute__((ext_vector_type(8))) short bf16x8;
typedef __attribute__((ext_vector_type(4))) float floatx4;

#define TB 4096      // tokens per batch
#define RECS 528     // shorts per packed record (1056 B)

__device__ __forceinline__ float b2f(ushort u) {
    union { unsigned int u; float f; } c; c.u = ((unsigned int)u) << 16; return c.f;
}
__device__ __forceinline__ ushort f2b(float f) {
    union { float f; unsigned int u; } c; c.f = f;
    unsigned int r = (c.u + 0x7fffu + ((c.u >> 16) & 1u)) >> 16;
    return (ushort)r;
}
__device__ __forceinline__ float silu(float x) { return x / (1.0f + expf(-x)); }

// ---------------------------------------------------------------------------
__global__ __launch_bounds__(256) void cast_f32_bf16(const float* __restrict__ in,
                                                     ushort* __restrict__ out, int n) {
    int i = (blockIdx.x * 256 + threadIdx.x) * 4;
    int stride = gridDim.x * 256 * 4;
    for (; i + 3 < n; i += stride) {
        float4 v = *(const float4*)(in + i);
        ushort4 u;
        u.x = f2b(v.x); u.y = f2b(v.y); u.z = f2b(v.z); u.w = f2b(v.w);
        *(ushort4*)(out + i) = u;
    }
}

// ---------------------------------------------------------------------------
// bf16 MFMA GEMM: C[M][N] = A[M][K] @ B[N][K]^T  (row-major, K contiguous)
// 128x128 tile, BK=32, 4 waves, each wave 64x64 (4x4 16x16x32 frags)
// ---------------------------------------------------------------------------
template <typename CT>
__global__ __launch_bounds__(256) void gemm_bf16(const ushort* __restrict__ A,
                                                 const ushort* __restrict__ B,
                                                 CT* __restrict__ C, int M, int N, int K) {
    __shared__ ushort As[128 * 40];
    __shared__ ushort Bs[128 * 40];
    const int tid = threadIdx.x;
    const int lane = tid & 63, wid = tid >> 6;
    const int wr = wid >> 1, wc = wid & 1;
    const int bm = blockIdx.y, bn = blockIdx.x;

    const int r0 = tid >> 2;
    const int kc0 = (tid & 3) * 8;
    const size_t aoff0 = (size_t)(bm * 128 + r0) * K + kc0;
    const size_t aoff1 = aoff0 + (size_t)64 * K;
    const size_t boff0 = (size_t)(bn * 128 + r0) * K + kc0;
    const size_t boff1 = boff0 + (size_t)64 * K;
    const int lw0 = r0 * 40 + kc0;
    const int lw1 = (r0 + 64) * 40 + kc0;

    const int arow = wr * 64 + (lane & 15);
    const int brow = wc * 64 + (lane & 15);
    const int kg = (lane >> 4) * 8;

    floatx4 acc[4][4];
#pragma unroll
    for (int m = 0; m < 4; ++m)
#pragma unroll
        for (int n = 0; n < 4; ++n) acc[m][n] = (floatx4){0.f, 0.f, 0.f, 0.f};

    uint4 ra0 = *(const uint4*)(A + aoff0);
    uint4 ra1 = *(const uint4*)(A + aoff1);
    uint4 rb0 = *(const uint4*)(B + boff0);
    uint4 rb1 = *(const uint4*)(B + boff1);

    for (int kt = 32; kt <= K; kt += 32) {
        __syncthreads();
        *(uint4*)(As + lw0) = ra0;
        *(uint4*)(As + lw1) = ra1;
        *(uint4*)(Bs + lw0) = rb0;
        *(uint4*)(Bs + lw1) = rb1;
        __syncthreads();
        if (kt < K) {
            ra0 = *(const uint4*)(A + aoff0 + kt);
            ra1 = *(const uint4*)(A + aoff1 + kt);
            rb0 = *(const uint4*)(B + boff0 + kt);
            rb1 = *(const uint4*)(B + boff1 + kt);
        }
        bf16x8 af[4], bfr[4];
#pragma unroll
        for (int m = 0; m < 4; ++m) af[m] = *(const bf16x8*)(As + (arow + m * 16) * 40 + kg);
#pragma unroll
        for (int n = 0; n < 4; ++n) bfr[n] = *(const bf16x8*)(Bs + (brow + n * 16) * 40 + kg);
#pragma unroll
        for (int m = 0; m < 4; ++m)
#pragma unroll
            for (int n = 0; n < 4; ++n)
                acc[m][n] = __builtin_amdgcn_mfma_f32_16x16x32_bf16(af[m], bfr[n], acc[m][n], 0, 0, 0);
    }

    const int crow0 = bm * 128 + wr * 64 + (lane >> 4) * 4;
    const int ccol0 = bn * 128 + wc * 64 + (lane & 15);
#pragma unroll
    for (int m = 0; m < 4; ++m)
#pragma unroll
        for (int n = 0; n < 4; ++n)
#pragma unroll
            for (int j = 0; j < 4; ++j) {
                int row = crow0 + m * 16 + j;
                int col = ccol0 + n * 16;
                if constexpr (sizeof(CT) == 2)
                    C[(size_t)row * N + col] = (CT)f2b(acc[m][n][j]);
                else
                    C[(size_t)row * N + col] = (CT)acc[m][n][j];
            }
}

// ---------------------------------------------------------------------------
// fused conv+silu + surprise stats + beta/amp MLPs -> packed records.
// one wave per (t,h) of this batch; lane owns dims {lane, lane+64}
// ---------------------------------------------------------------------------
__global__ __launch_bounds__(256) void conv_stats_kernel(
    const ushort* __restrict__ qkv,   // [TB][6144] bf16 (q|k|v), this batch
    const float* __restrict__ convq, const float* __restrict__ convk,
    const float* __restrict__ convv, const float* __restrict__ Wsv,
    const float* __restrict__ Wb1, const float* __restrict__ bb1,
    const float* __restrict__ Wb2, const float* __restrict__ bb2,
    const float* __restrict__ Wa1, const float* __restrict__ ba1,
    const float* __restrict__ Wa2, const float* __restrict__ ba2,
    const float* __restrict__ A_log, const float* __restrict__ dt_bias,
    ushort* __restrict__ P) {        // [16][TB][RECS]
    __shared__ ushort wsv_s[128 * 136];
    __shared__ float k_sh[4][128];
    for (int i = threadIdx.x; i < 128 * 128; i += 256) {
        int row = i >> 7, col = i & 127;
        wsv_s[row * 136 + col] = f2b(Wsv[i]);
    }
    __syncthreads();
    const int wid = threadIdx.x >> 6, lane = threadIdx.x & 63;

    for (int it = 0; it < 2; ++it) {
        const int pair = blockIdx.x * 8 + it * 4 + wid;   // [0, TB*16)
        const int t = pair >> 4, h = pair & 15;
        const int c0 = h * 128 + lane, c1 = c0 + 64;

        float wq[4], wq2[4], wk[4], wk2[4], wv[4], wv2[4];
#pragma unroll
        for (int i2 = 0; i2 < 4; ++i2) {
            wq[i2] = convq[c0 * 4 + i2]; wq2[i2] = convq[c1 * 4 + i2];
            wk[i2] = convk[c0 * 4 + i2]; wk2[i2] = convk[c1 * 4 + i2];
            wv[i2] = convv[c0 * 4 + i2]; wv2[i2] = convv[c1 * 4 + i2];
        }
        float aq0 = 0, aq1 = 0, ak0 = 0, ak1 = 0, av0 = 0, av1 = 0;
#pragma unroll
        for (int i2 = 0; i2 < 4; ++i2) {
            int tt = t - 3 + i2;
            if (tt >= 0) {
                const ushort* rowp = qkv + (size_t)tt * 6144 + h * 128;
                aq0 = fmaf(b2f(rowp[lane]), wq[i2], aq0);
                aq1 = fmaf(b2f(rowp[lane + 64]), wq2[i2], aq1);
                ak0 = fmaf(b2f(rowp[2048 + lane]), wk[i2], ak0);
                ak1 = fmaf(b2f(rowp[2048 + lane + 64]), wk2[i2], ak1);
                av0 = fmaf(b2f(rowp[4096 + lane]), wv[i2], av0);
                av1 = fmaf(b2f(rowp[4096 + lane + 64]), wv2[i2], av1);
            }
        }
        float q0 = silu(aq0), q1 = silu(aq1);
        float k0 = silu(ak0), k1 = silu(ak1);
        float v0 = silu(av0), v1 = silu(av1);

        __syncthreads();
        k_sh[wid][lane] = k0;
        k_sh[wid][lane + 64] = k1;
        __syncthreads();

        float vh0 = 0.f, vh1 = 0.f;
        const ushort* wr0 = wsv_s + lane * 136;
        const ushort* wr1 = wsv_s + (lane + 64) * 136;
#pragma unroll 4
        for (int j = 0; j < 128; j += 8) {
            float4 ka = *(const float4*)&k_sh[wid][j];
            float4 kb = *(const float4*)&k_sh[wid][j + 4];
            uint4 wa = *(const uint4*)(wr0 + j);
            uint4 wb = *(const uint4*)(wr1 + j);
            vh0 = fmaf(__uint_as_float(wa.x << 16), ka.x, vh0);
            vh0 = fmaf(__uint_as_float(wa.x & 0xffff0000u), ka.y, vh0);
            vh0 = fmaf(__uint_as_float(wa.y << 16), ka.z, vh0);
            vh0 = fmaf(__uint_as_float(wa.y & 0xffff0000u), ka.w, vh0);
            vh0 = fmaf(__uint_as_float(wa.z << 16), kb.x, vh0);
            vh0 = fmaf(__uint_as_float(wa.z & 0xffff0000u), kb.y, vh0);
            vh0 = fmaf(__uint_as_float(wa.w << 16), kb.z, vh0);
            vh0 = fmaf(__uint_as_float(wa.w & 0xffff0000u), kb.w, vh0);
            vh1 = fmaf(__uint_as_float(wb.x << 16), ka.x, vh1);
            vh1 = fmaf(__uint_as_float(wb.x & 0xffff0000u), ka.y, vh1);
            vh1 = fmaf(__uint_as_float(wb.y << 16), ka.z, vh1);
            vh1 = fmaf(__uint_as_float(wb.y & 0xffff0000u), ka.w, vh1);
            vh1 = fmaf(__uint_as_float(wb.z << 16), kb.x, vh1);
            vh1 = fmaf(__uint_as_float(wb.z & 0xffff0000u), kb.y, vh1);
            vh1 = fmaf(__uint_as_float(wb.w << 16), kb.z, vh1);
            vh1 = fmaf(__uint_as_float(wb.w & 0xffff0000u), kb.w, vh1);
        }

        float e0 = vh0 - v0, e1 = vh1 - v1;
        float se2 = e0 * e0 + e1 * e1;
        float sl1 = fabsf(e0) + fabsf(e1);
        float shv = vh0 * v0 + vh1 * v1;
        float shh = vh0 * vh0 + vh1 * vh1;
        float svv = v0 * v0 + v1 * v1;
        float sk2 = k0 * k0 + k1 * k1;
        float sq2 = q0 * q0 + q1 * q1;
#pragma unroll
        for (int m = 32; m >= 1; m >>= 1) {
            se2 += __shfl_xor(se2, m);
            sl1 += __shfl_xor(sl1, m);
            shv += __shfl_xor(shv, m);
            shh += __shfl_xor(shh, m);
            svv += __shfl_xor(svv, m);
            sk2 += __shfl_xor(sk2, m);
            sq2 += __shfl_xor(sq2, m);
        }
        float s_l2 = sqrtf(se2 + 1e-6f);
        float s_l1 = sl1;
        float s_cos = 1.0f - shv / (sqrtf(shh + 1e-6f) * sqrtf(svv + 1e-6f) + 1e-6f);

        // two tiny MLPs: lanes 0-31 beta, lanes 32-63 amp
        const int j2 = lane & 31;
        const float* W1 = (lane < 32) ? Wb1 : Wa1;
        const float* b1 = (lane < 32) ? bb1 : ba1;
        const float* W2 = (lane < 32) ? Wb2 : Wa2;
        float pre = W1[j2 * 3] * s_l2 + W1[j2 * 3 + 1] * s_l1 + W1[j2 * 3 + 2] * s_cos + b1[j2];
        float val = W2[j2] * silu(pre);
#pragma unroll
        for (int m = 16; m >= 1; m >>= 1) val += __shfl_xor(val, m);
        float pre_b = __shfl(val, 0) + bb2[0];
        float pre_a = __shfl(val, 32) + ba2[0];
        float betav = 1.0f / (1.0f + expf(-pre_b));
        float amp = pre_a;

        float knorm = sqrtf(sk2);
        float rinv = amp / fmaxf(knorm, 1e-12f);
        float ah = expf(A_log[h]);
        float gr0 = fmaf(k0, rinv, dt_bias[c0]);
        float gr1 = fmaf(k1, rinv, dt_bias[c1]);
        float sp0 = (gr0 > 20.f) ? gr0 : log1pf(expf(gr0));
        float sp1 = (gr1 > 20.f) ? gr1 : log1pf(expf(gr1));
        float g0v = -ah * sp0;     // store log-decay (bf16-safe: see notes)
        float g1v = -ah * sp1;

        ushort* rec = P + ((size_t)h * TB + t) * RECS;
        float kinv = rsqrtf(sk2 + 1e-6f);
        rec[lane]       = f2b(k0 * kinv);
        rec[lane + 64]  = f2b(k1 * kinv);
        float qinv = rsqrtf(sq2 + 1e-6f) * 0.08838834764831845f;  // * DK^-0.5
        rec[128 + lane]      = f2b(q0 * qinv);
        rec[128 + lane + 64] = f2b(q1 * qinv);
        rec[256 + lane]      = f2b(v0);
        rec[256 + lane + 64] = f2b(v1);
        rec[384 + lane]      = f2b(g0v);
        rec[384 + lane + 64] = f2b(g1v);
        if (lane == 0) *(float*)(rec + 512) = betav;
    }
}

// ---------------------------------------------------------------------------
// sequential delta-rule scan (one batch); S columns independent ->
// 256 blocks = (h, 16 chunks of 8 v-cols); thread: col = chunk*8 + tid>>5,
// rows (tid&31)*4..+3.  o out: [TB][2048] bf16.
// ---------------------------------------------------------------------------
__global__ __launch_bounds__(256) void scan_kernel(const ushort* __restrict__ P,
                                                   ushort* __restrict__ o) {
    const int bid = blockIdx.x;
    const int h = bid >> 4, chunk = bid & 15;
    const int tid = threadIdx.x;
    const int cl = tid >> 5, r = tid & 31;
    const int col = chunk * 8 + cl;
    const ushort* Pb = P + (size_t)h * TB * RECS;
    ushort* op = o + h * 128 + col;

    float S0 = 0.f, S1 = 0.f, S2 = 0.f, S3 = 0.f;
    ushort4 kr = *(const ushort4*)(Pb + r * 4);
    ushort4 qr = *(const ushort4*)(Pb + 128 + r * 4);
    ushort vr = Pb[256 + col];
    ushort4 gr = *(const ushort4*)(Pb + 384 + r * 4);
    float br = *(const float*)(Pb + 512);

    for (int t = 0; t < TB; ++t) {
        float kc0 = b2f(kr.x), kc1 = b2f(kr.y), kc2 = b2f(kr.z), kc3 = b2f(kr.w);
        float qc0 = b2f(qr.x), qc1 = b2f(qr.y), qc2 = b2f(qr.z), qc3 = b2f(qr.w);
        float e0 = expf(b2f(gr.x)), e1 = expf(b2f(gr.y));
        float e2 = expf(b2f(gr.z)), e3 = expf(b2f(gr.w));
        float vc = b2f(vr), bc = br;
        if (t + 1 < TB) {
            const ushort* rec = Pb + (size_t)(t + 1) * RECS;
            kr = *(const ushort4*)(rec + r * 4);
            qr = *(const ushort4*)(rec + 128 + r * 4);
            vr = rec[256 + col];
            gr = *(const ushort4*)(rec + 384 + r * 4);
            br = *(const float*)(rec + 512);
        }
        S0 *= e0; S1 *= e1; S2 *= e2; S3 *= e3;
        float p = fmaf(S0, kc0, fmaf(S1, kc1, fmaf(S2, kc2, S3 * kc3)));
        p += __shfl_xor(p, 1); p += __shfl_xor(p, 2); p += __shfl_xor(p, 4);
        p += __shfl_xor(p, 8); p += __shfl_xor(p, 16);
        float delta = (vc - p) * bc;
        S0 = fmaf(kc0, delta, S0); S1 = fmaf(kc1, delta, S1);
        S2 = fmaf(kc2, delta, S2); S3 = fmaf(kc3, delta, S3);
        float oo = fmaf(S0, qc0, fmaf(S1, qc1, fmaf(S2, qc2, S3 * qc3)));
        oo += __shfl_xor(oo, 1); oo += __shfl_xor(oo, 2); oo += __shfl_xor(oo, 4);
        oo += __shfl_xor(oo, 8); oo += __shfl_xor(oo, 16);
        if (r == 0) op[(size_t)t * 2048] = f2b(oo);
    }
}

// ---------------------------------------------------------------------------
// gated RMS norm (one batch): og = bf16( o*rsqrt(mean o^2+1e-5)*norm_w*sigmoid(gate+bg2) )
// ---------------------------------------------------------------------------
__global__ __launch_bounds__(256) void normgate_kernel(
    const ushort* __restrict__ o, const ushort* __restrict__ gate,
    const float* __restrict__ bg2, const float* __restrict__ norm_w,
    ushort* __restrict__ og) {
    const int lane = threadIdx.x & 63;
    const int wstart = (blockIdx.x * 256 + threadIdx.x) >> 6;
    const int nw = (gridDim.x * 256) >> 6;
    for (int pair = wstart; pair < TB * 16; pair += nw) {
        const int t = pair >> 4, h = pair & 15;
        const size_t basep = (size_t)t * 2048 + h * 128 + lane * 2;
        unsigned int ovu = *(const unsigned int*)(o + basep);
        float o0 = __uint_as_float(ovu << 16);
        float o1 = __uint_as_float(ovu & 0xffff0000u);
        float ss = o0 * o0 + o1 * o1;
#pragma unroll
        for (int m = 32; m >= 1; m >>= 1) ss += __shfl_xor(ss, m);
        float rn = rsqrtf(ss * (1.0f / 128.0f) + 1e-5f);
        const int dg = h * 128 + lane * 2;
        unsigned int gv = *(const unsigned int*)(gate + basep);
        float g0 = __uint_as_float(gv << 16) + bg2[dg];
        float g1 = __uint_as_float(gv & 0xffff0000u) + bg2[dg + 1];
        float w0 = norm_w[lane * 2], w1 = norm_w[lane * 2 + 1];
        float r0 = o0 * rn * w0 / (1.0f + expf(-g0));
        float r1 = o1 * rn * w1 / (1.0f + expf(-g1));
        unsigned int outw = (unsigned int)f2b(r0) | ((unsigned int)f2b(r1) << 16);
        *(unsigned int*)(og + basep) = outw;
    }
}

// ---------------------------------------------------------------------------
extern "C" void kernel_launch(void* const* d_in, const int* in_sizes, int n_in,
                              void* d_out, int out_size, void* d_ws, size_t ws_size,
                              hipStream_t stream) {
    const float* x = (const float*)d_in[0];
    const float* Wq = (const float*)d_in[1];
    const float* Wk = (const float*)d_in[2];
    const float* Wv = (const float*)d_in[3];
    const float* convq = (const float*)d_in[4];
    const float* convk = (const float*)d_in[5];
    const float* convv = (const float*)d_in[6];
    const float* A_log = (const float*)d_in[7];
    const float* dt_bias = (const float*)d_in[8];
    const float* Wsv = (const float*)d_in[9];
    const float* Wb1 = (const float*)d_in[10];
    const float* bb1 = (const float*)d_in[11];
    const float* Wb2 = (const float*)d_in[12];
    const float* bb2 = (const float*)d_in[13];
    const float* Wa1 = (const float*)d_in[14];
    const float* ba1 = (const float*)d_in[15];
    const float* Wa2 = (const float*)d_in[16];
    const float* ba2 = (const float*)d_in[17];
    const float* Wg1 = (const float*)d_in[18];
    const float* Wg2 = (const float*)d_in[19];
    const float* bg2 = (const float*)d_in[20];
    const float* norm_w = (const float*)d_in[21];
    const float* Wo = (const float*)d_in[22];

    // ---- static workspace layout (bytes) ----
    const size_t OFF_WQKV = 0;                         // 25,165,824
    const size_t OFF_WG1  = OFF_WQKV + 25165824;       //    524,288
    const size_t OFF_WG2  = OFF_WG1 + 524288;          //    524,288
    const size_t OFF_WO   = OFF_WG2 + 524288;          //  8,388,608
    const size_t OFF_XB   = OFF_WO + 8388608;          // 16,777,216
    const size_t OFF_QKV  = OFF_XB + 16777216;         // 50,331,648
    const size_t OFF_P    = OFF_QKV + 50331648;        // 69,206,016
    const size_t OFF_OB   = OFF_P + 69206016;          // 16,777,216
    const size_t OFF_XG1  = OFF_OB + 16777216;         //  1,048,576
    const size_t NEED     = OFF_XG1 + 1048576;         // 188,743,680 total
    if (ws_size < NEED) return;  // diagnostic guard: fail with untouched output

    char* ws = (char*)d_ws;
    ushort* wqkv = (ushort*)(ws + OFF_WQKV);
    ushort* wg1b = (ushort*)(ws + OFF_WG1);
    ushort* wg2b = (ushort*)(ws + OFF_WG2);
    ushort* wob  = (ushort*)(ws + OFF_WO);
    ushort* xb   = (ushort*)(ws + OFF_XB);
    ushort* qkvb = (ushort*)(ws + OFF_QKV);
    ushort* P    = (ushort*)(ws + OFF_P);
    ushort* ob   = (ushort*)(ws + OFF_OB);
    ushort* xg1b = (ushort*)(ws + OFF_XG1);
    // aliases into qkvb (dead after conv_stats within each b-iteration):
    ushort* gateb = qkvb;
    ushort* ogb   = qkvb + 16777216 / 2;

    // ---- weight casts (once) ----
    cast_f32_bf16<<<512, 256, 0, stream>>>(Wq, wqkv, 4194304);
    cast_f32_bf16<<<512, 256, 0, stream>>>(Wk, wqkv + 4194304, 4194304);
    cast_f32_bf16<<<512, 256, 0, stream>>>(Wv, wqkv + 8388608, 4194304);
    cast_f32_bf16<<<64, 256, 0, stream>>>(Wg1, wg1b, 262144);
    cast_f32_bf16<<<64, 256, 0, stream>>>(Wg2, wg2b, 262144);
    cast_f32_bf16<<<512, 256, 0, stream>>>(Wo, wob, 4194304);

    for (int b = 0; b < 2; ++b) {
        const float* xbp = x + (size_t)b * TB * 2048;
        float* outp = (float*)d_out + (size_t)b * TB * 2048;

        cast_f32_bf16<<<512, 256, 0, stream>>>(xbp, xb, TB * 2048);

        // qkv projection: [TB][6144] = xb @ wqkv^T
        gemm_bf16<ushort><<<dim3(48, TB / 128), 256, 0, stream>>>(xb, wqkv, qkvb, TB, 6144, 2048);

        // conv + stats + gates -> packed records
        conv_stats_kernel<<<TB * 16 / 8, 256, 0, stream>>>(qkvb, convq, convk, convv, Wsv,
                                                           Wb1, bb1, Wb2, bb2, Wa1, ba1, Wa2, ba2,
                                                           A_log, dt_bias, P);

        // sequential scan -> ob (bf16 [TB][2048])
        scan_kernel<<<256, 256, 0, stream>>>(P, ob);

        // gate GEMMs (overwrite qkvb region — safe, conv done)
        gemm_bf16<ushort><<<dim3(1, TB / 128), 256, 0, stream>>>(xb, wg1b, xg1b, TB, 128, 2048);
        gemm_bf16<ushort><<<dim3(16, TB / 128), 256, 0, stream>>>(xg1b, wg2b, gateb, TB, 2048, 128);

        // norm + gate -> ogb
        normgate_kernel<<<2048, 256, 0, stream>>>(ob, gateb, bg2, norm_w, ogb);

        // output projection -> d_out (fp32)
        gemm_bf16<float><<<dim3(16, TB / 128), 256, 0, stream>>>(ogb, wob, outp, TB, 2048, 2048);
    }
}

// Round 3
// 5321.552 us; speedup vs baseline: 1.1534x; 1.1534x over previous
//
#include <hip/hip_runtime.h>
#include <hip/hip_bf16.h>

// ---------------------------------------------------------------------------
// SurpriseKimiDeltaAttention  (B=2, T=4096, H=2048, NH=16, DK=DV=128, CONV=4)
//  1. cast weights + x to bf16
//  2. GEMM qkv = x @ [Wq;Wk;Wv]^T            (bf16 MFMA)
//  3. fused conv+silu + surprise stats + MLPs -> packed records P:
//     per (h,t): kn|qn*scale|g|v  (128 bf16 each) + beta f32 + qk f32
//  4. delta-rule scan, latency-optimized:
//     o = q^T S_dec + (q.k)*delta  (single 16-lane reduction depth, 2-deep
//     load pipeline, exp off critical path)
//  5. gate GEMMs, RMS-norm*sigmoid(gate), output GEMM
// Plan A (ws >= ~273MB): both batches' P resident, ONE scan launch.
// Plan B (ws >= ~188MB): per-batch sequential (two scan launches).
// ---------------------------------------------------------------------------

typedef __attribute__((ext_vector_type(8))) short bf16x8;
typedef __attribute__((ext_vector_type(4))) float floatx4;

#define TB 4096      // tokens per batch
#define RECS 520     // shorts per packed record (1040 B): k|q|g|v|beta,qk
#define PSTRIDE ((size_t)16 * TB * RECS)   // shorts per batch of P

__device__ __forceinline__ float b2f(ushort u) {
    union { unsigned int u; float f; } c; c.u = ((unsigned int)u) << 16; return c.f;
}
__device__ __forceinline__ ushort f2b(float f) {
    union { float f; unsigned int u; } c; c.f = f;
    unsigned int r = (c.u + 0x7fffu + ((c.u >> 16) & 1u)) >> 16;
    return (ushort)r;
}
__device__ __forceinline__ float silu(float x) { return x / (1.0f + expf(-x)); }

// ---------------------------------------------------------------------------
__global__ __launch_bounds__(256) void cast_f32_bf16(const float* __restrict__ in,
                                                     ushort* __restrict__ out, int n) {
    int i = (blockIdx.x * 256 + threadIdx.x) * 4;
    int stride = gridDim.x * 256 * 4;
    for (; i + 3 < n; i += stride) {
        float4 v = *(const float4*)(in + i);
        ushort4 u;
        u.x = f2b(v.x); u.y = f2b(v.y); u.z = f2b(v.z); u.w = f2b(v.w);
        *(ushort4*)(out + i) = u;
    }
}

// ---------------------------------------------------------------------------
// bf16 MFMA GEMM: C[M][N] = A[M][K] @ B[N][K]^T  (row-major, K contiguous)
// ---------------------------------------------------------------------------
template <typename CT>
__global__ __launch_bounds__(256) void gemm_bf16(const ushort* __restrict__ A,
                                                 const ushort* __restrict__ B,
                                                 CT* __restrict__ C, int M, int N, int K) {
    __shared__ ushort As[128 * 40];
    __shared__ ushort Bs[128 * 40];
    const int tid = threadIdx.x;
    const int lane = tid & 63, wid = tid >> 6;
    const int wr = wid >> 1, wc = wid & 1;
    const int bm = blockIdx.y, bn = blockIdx.x;

    const int r0 = tid >> 2;
    const int kc0 = (tid & 3) * 8;
    const size_t aoff0 = (size_t)(bm * 128 + r0) * K + kc0;
    const size_t aoff1 = aoff0 + (size_t)64 * K;
    const size_t boff0 = (size_t)(bn * 128 + r0) * K + kc0;
    const size_t boff1 = boff0 + (size_t)64 * K;
    const int lw0 = r0 * 40 + kc0;
    const int lw1 = (r0 + 64) * 40 + kc0;

    const int arow = wr * 64 + (lane & 15);
    const int brow = wc * 64 + (lane & 15);
    const int kg = (lane >> 4) * 8;

    floatx4 acc[4][4];
#pragma unroll
    for (int m = 0; m < 4; ++m)
#pragma unroll
        for (int n = 0; n < 4; ++n) acc[m][n] = (floatx4){0.f, 0.f, 0.f, 0.f};

    uint4 ra0 = *(const uint4*)(A + aoff0);
    uint4 ra1 = *(const uint4*)(A + aoff1);
    uint4 rb0 = *(const uint4*)(B + boff0);
    uint4 rb1 = *(const uint4*)(B + boff1);

    for (int kt = 32; kt <= K; kt += 32) {
        __syncthreads();
        *(uint4*)(As + lw0) = ra0;
        *(uint4*)(As + lw1) = ra1;
        *(uint4*)(Bs + lw0) = rb0;
        *(uint4*)(Bs + lw1) = rb1;
        __syncthreads();
        if (kt < K) {
            ra0 = *(const uint4*)(A + aoff0 + kt);
            ra1 = *(const uint4*)(A + aoff1 + kt);
            rb0 = *(const uint4*)(B + boff0 + kt);
            rb1 = *(const uint4*)(B + boff1 + kt);
        }
        bf16x8 af[4], bfr[4];
#pragma unroll
        for (int m = 0; m < 4; ++m) af[m] = *(const bf16x8*)(As + (arow + m * 16) * 40 + kg);
#pragma unroll
        for (int n = 0; n < 4; ++n) bfr[n] = *(const bf16x8*)(Bs + (brow + n * 16) * 40 + kg);
#pragma unroll
        for (int m = 0; m < 4; ++m)
#pragma unroll
            for (int n = 0; n < 4; ++n)
                acc[m][n] = __builtin_amdgcn_mfma_f32_16x16x32_bf16(af[m], bfr[n], acc[m][n], 0, 0, 0);
    }

    const int crow0 = bm * 128 + wr * 64 + (lane >> 4) * 4;
    const int ccol0 = bn * 128 + wc * 64 + (lane & 15);
#pragma unroll
    for (int m = 0; m < 4; ++m)
#pragma unroll
        for (int n = 0; n < 4; ++n)
#pragma unroll
            for (int j = 0; j < 4; ++j) {
                int row = crow0 + m * 16 + j;
                int col = ccol0 + n * 16;
                if constexpr (sizeof(CT) == 2)
                    C[(size_t)row * N + col] = (CT)f2b(acc[m][n][j]);
                else
                    C[(size_t)row * N + col] = (CT)acc[m][n][j];
            }
}

// ---------------------------------------------------------------------------
// fused conv+silu + surprise stats + beta/amp MLPs -> packed records
// ---------------------------------------------------------------------------
__global__ __launch_bounds__(256) void conv_stats_kernel(
    const ushort* __restrict__ qkv,   // [TB][6144] bf16 (q|k|v), this batch
    const float* __restrict__ convq, const float* __restrict__ convk,
    const float* __restrict__ convv, const float* __restrict__ Wsv,
    const float* __restrict__ Wb1, const float* __restrict__ bb1,
    const float* __restrict__ Wb2, const float* __restrict__ bb2,
    const float* __restrict__ Wa1, const float* __restrict__ ba1,
    const float* __restrict__ Wa2, const float* __restrict__ ba2,
    const float* __restrict__ A_log, const float* __restrict__ dt_bias,
    ushort* __restrict__ P) {        // [16][TB][RECS]
    __shared__ ushort wsv_s[128 * 136];
    __shared__ float k_sh[4][128];
    for (int i = threadIdx.x; i < 128 * 128; i += 256) {
        int row = i >> 7, col = i & 127;
        wsv_s[row * 136 + col] = f2b(Wsv[i]);
    }
    __syncthreads();
    const int wid = threadIdx.x >> 6, lane = threadIdx.x & 63;

    for (int it = 0; it < 2; ++it) {
        const int pair = blockIdx.x * 8 + it * 4 + wid;   // [0, TB*16)
        const int t = pair >> 4, h = pair & 15;
        const int c0 = h * 128 + lane, c1 = c0 + 64;

        float wq[4], wq2[4], wk[4], wk2[4], wv[4], wv2[4];
#pragma unroll
        for (int i2 = 0; i2 < 4; ++i2) {
            wq[i2] = convq[c0 * 4 + i2]; wq2[i2] = convq[c1 * 4 + i2];
            wk[i2] = convk[c0 * 4 + i2]; wk2[i2] = convk[c1 * 4 + i2];
            wv[i2] = convv[c0 * 4 + i2]; wv2[i2] = convv[c1 * 4 + i2];
        }
        float aq0 = 0, aq1 = 0, ak0 = 0, ak1 = 0, av0 = 0, av1 = 0;
#pragma unroll
        for (int i2 = 0; i2 < 4; ++i2) {
            int tt = t - 3 + i2;
            if (tt >= 0) {
                const ushort* rowp = qkv + (size_t)tt * 6144 + h * 128;
                aq0 = fmaf(b2f(rowp[lane]), wq[i2], aq0);
                aq1 = fmaf(b2f(rowp[lane + 64]), wq2[i2], aq1);
                ak0 = fmaf(b2f(rowp[2048 + lane]), wk[i2], ak0);
                ak1 = fmaf(b2f(rowp[2048 + lane + 64]), wk2[i2], ak1);
                av0 = fmaf(b2f(rowp[4096 + lane]), wv[i2], av0);
                av1 = fmaf(b2f(rowp[4096 + lane + 64]), wv2[i2], av1);
            }
        }
        float q0 = silu(aq0), q1 = silu(aq1);
        float k0 = silu(ak0), k1 = silu(ak1);
        float v0 = silu(av0), v1 = silu(av1);

        __syncthreads();
        k_sh[wid][lane] = k0;
        k_sh[wid][lane + 64] = k1;
        __syncthreads();

        float vh0 = 0.f, vh1 = 0.f;
        const ushort* wr0 = wsv_s + lane * 136;
        const ushort* wr1 = wsv_s + (lane + 64) * 136;
#pragma unroll 4
        for (int j = 0; j < 128; j += 8) {
            float4 ka = *(const float4*)&k_sh[wid][j];
            float4 kb = *(const float4*)&k_sh[wid][j + 4];
            uint4 wa = *(const uint4*)(wr0 + j);
            uint4 wb = *(const uint4*)(wr1 + j);
            vh0 = fmaf(__uint_as_float(wa.x << 16), ka.x, vh0);
            vh0 = fmaf(__uint_as_float(wa.x & 0xffff0000u), ka.y, vh0);
            vh0 = fmaf(__uint_as_float(wa.y << 16), ka.z, vh0);
            vh0 = fmaf(__uint_as_float(wa.y & 0xffff0000u), ka.w, vh0);
            vh0 = fmaf(__uint_as_float(wa.z << 16), kb.x, vh0);
            vh0 = fmaf(__uint_as_float(wa.z & 0xffff0000u), kb.y, vh0);
            vh0 = fmaf(__uint_as_float(wa.w << 16), kb.z, vh0);
            vh0 = fmaf(__uint_as_float(wa.w & 0xffff0000u), kb.w, vh0);
            vh1 = fmaf(__uint_as_float(wb.x << 16), ka.x, vh1);
            vh1 = fmaf(__uint_as_float(wb.x & 0xffff0000u), ka.y, vh1);
            vh1 = fmaf(__uint_as_float(wb.y << 16), ka.z, vh1);
            vh1 = fmaf(__uint_as_float(wb.y & 0xffff0000u), ka.w, vh1);
            vh1 = fmaf(__uint_as_float(wb.z << 16), kb.x, vh1);
            vh1 = fmaf(__uint_as_float(wb.z & 0xffff0000u), kb.y, vh1);
            vh1 = fmaf(__uint_as_float(wb.w << 16), kb.z, vh1);
            vh1 = fmaf(__uint_as_float(wb.w & 0xffff0000u), kb.w, vh1);
        }

        float e0 = vh0 - v0, e1 = vh1 - v1;
        float se2 = e0 * e0 + e1 * e1;
        float sl1 = fabsf(e0) + fabsf(e1);
        float shv = vh0 * v0 + vh1 * v1;
        float shh = vh0 * vh0 + vh1 * vh1;
        float svv = v0 * v0 + v1 * v1;
        float sk2 = k0 * k0 + k1 * k1;
        float sq2 = q0 * q0 + q1 * q1;
        float sqk = q0 * k0 + q1 * k1;
#pragma unroll
        for (int m = 32; m >= 1; m >>= 1) {
            se2 += __shfl_xor(se2, m);
            sl1 += __shfl_xor(sl1, m);
            shv += __shfl_xor(shv, m);
            shh += __shfl_xor(shh, m);
            svv += __shfl_xor(svv, m);
            sk2 += __shfl_xor(sk2, m);
            sq2 += __shfl_xor(sq2, m);
            sqk += __shfl_xor(sqk, m);
        }
        float s_l2 = sqrtf(se2 + 1e-6f);
        float s_l1 = sl1;
        float s_cos = 1.0f - shv / (sqrtf(shh + 1e-6f) * sqrtf(svv + 1e-6f) + 1e-6f);

        const int j2 = lane & 31;
        const float* W1 = (lane < 32) ? Wb1 : Wa1;
        const float* b1 = (lane < 32) ? bb1 : ba1;
        const float* W2 = (lane < 32) ? Wb2 : Wa2;
        float pre = W1[j2 * 3] * s_l2 + W1[j2 * 3 + 1] * s_l1 + W1[j2 * 3 + 2] * s_cos + b1[j2];
        float val = W2[j2] * silu(pre);
#pragma unroll
        for (int m = 16; m >= 1; m >>= 1) val += __shfl_xor(val, m);
        float pre_b = __shfl(val, 0) + bb2[0];
        float pre_a = __shfl(val, 32) + ba2[0];
        float betav = 1.0f / (1.0f + expf(-pre_b));
        float amp = pre_a;

        float knorm = sqrtf(sk2);
        float rinv = amp / fmaxf(knorm, 1e-12f);
        float ah = expf(A_log[h]);
        float gr0 = fmaf(k0, rinv, dt_bias[c0]);
        float gr1 = fmaf(k1, rinv, dt_bias[c1]);
        float sp0 = (gr0 > 20.f) ? gr0 : log1pf(expf(gr0));
        float sp1 = (gr1 > 20.f) ? gr1 : log1pf(expf(gr1));
        float g0v = -ah * sp0;     // log-decay, stored bf16
        float g1v = -ah * sp1;

        ushort* rec = P + ((size_t)h * TB + t) * RECS;
        float kinv = rsqrtf(sk2 + 1e-6f);
        float qinv = rsqrtf(sq2 + 1e-6f) * 0.08838834764831845f;  // * DK^-0.5
        rec[lane]            = f2b(k0 * kinv);
        rec[lane + 64]       = f2b(k1 * kinv);
        rec[128 + lane]      = f2b(q0 * qinv);
        rec[128 + lane + 64] = f2b(q1 * qinv);
        rec[256 + lane]      = f2b(g0v);
        rec[256 + lane + 64] = f2b(g1v);
        rec[384 + lane]      = f2b(v0);
        rec[384 + lane + 64] = f2b(v1);
        if (lane == 0) {
            *(float*)(rec + 512) = betav;
            *(float*)(rec + 514) = sqk * qinv * kinv;   // (qn*scale).kn
        }
    }
}

// ---------------------------------------------------------------------------
// delta-rule scan, latency-optimized.
// block: 256 thr = 16 colgroups x 16 lanes; each thread: 8 rows x 1 col.
// grid: nb*128 blocks; bid -> b = bid>>7; h = (bid>>3)&15; blk = bid&7;
// col = blk*16 + (tid>>4).  o out: [b][TB][2048] bf16.
// ---------------------------------------------------------------------------
struct RawRec { uint4 k, q, g; ushort v; float2 m; };
struct DecRec { float k[8], q[8], e[8]; float v, b, qk; };

__device__ __forceinline__ RawRec load_rec(const ushort* rec, int r0, int col) {
    RawRec r;
    r.k = *(const uint4*)(rec + r0);
    r.q = *(const uint4*)(rec + 128 + r0);
    r.g = *(const uint4*)(rec + 256 + r0);
    r.v = rec[384 + col];
    r.m = *(const float2*)(rec + 512);
    return r;
}
__device__ __forceinline__ DecRec decode(const RawRec& r) {
    DecRec d;
    const uint* kw = (const uint*)&r.k;
    const uint* qw = (const uint*)&r.q;
    const uint* gw = (const uint*)&r.g;
#pragma unroll
    for (int w = 0; w < 4; ++w) {
        d.k[2 * w]     = __uint_as_float(kw[w] << 16);
        d.k[2 * w + 1] = __uint_as_float(kw[w] & 0xffff0000u);
        d.q[2 * w]     = __uint_as_float(qw[w] << 16);
        d.q[2 * w + 1] = __uint_as_float(qw[w] & 0xffff0000u);
        float g0 = __uint_as_float(gw[w] << 16);
        float g1 = __uint_as_float(gw[w] & 0xffff0000u);
        d.e[2 * w]     = exp2f(g0 * 1.442695040888963f);
        d.e[2 * w + 1] = exp2f(g1 * 1.442695040888963f);
    }
    d.v = b2f(r.v);
    d.b = r.m.x;
    d.qk = r.m.y;
    return d;
}

__global__ __launch_bounds__(256) void scan_kernel(const ushort* __restrict__ P,
                                                   ushort* __restrict__ o) {
    const int bid = blockIdx.x;
    const int b = bid >> 7;
    const int h = (bid >> 3) & 15;
    const int blk = bid & 7;
    const int tid = threadIdx.x;
    const int lane16 = tid & 15;
    const int cg = tid >> 4;
    const int col = blk * 16 + cg;
    const int r0 = lane16 * 8;
    const ushort* Pb = P + (size_t)b * PSTRIDE + (size_t)h * TB * RECS;
    ushort* op = o + (size_t)b * TB * 2048 + h * 128 + col;

    float S[8];
#pragma unroll
    for (int j = 0; j < 8; ++j) S[j] = 0.f;

    RawRec rA = load_rec(Pb, r0, col);
    RawRec rB = load_rec(Pb + RECS, r0, col);
    DecRec dCur = decode(rA);

    auto step = [&](const DecRec& d, int t) {
        float pk0 = 0.f, pk1 = 0.f, pq0 = 0.f, pq1 = 0.f;
#pragma unroll
        for (int j = 0; j < 8; ++j) S[j] *= d.e[j];
#pragma unroll
        for (int j = 0; j < 4; ++j) {
            pk0 = fmaf(d.k[j], S[j], pk0);
            pk1 = fmaf(d.k[j + 4], S[j + 4], pk1);
            pq0 = fmaf(d.q[j], S[j], pq0);
            pq1 = fmaf(d.q[j + 4], S[j + 4], pq1);
        }
        float pk = pk0 + pk1, pq = pq0 + pq1;
#pragma unroll
        for (int m = 1; m <= 8; m <<= 1) {
            pk += __shfl_xor(pk, m);
            pq += __shfl_xor(pq, m);
        }
        float delta = (d.v - pk) * d.b;
        float oo = fmaf(d.qk, delta, pq);
#pragma unroll
        for (int j = 0; j < 8; ++j) S[j] = fmaf(d.k[j], delta, S[j]);
        if (lane16 == 0) op[(size_t)t * 2048] = f2b(oo);
    };

    for (int t = 0; t < TB; t += 2) {
        if (t + 2 < TB) rA = load_rec(Pb + (size_t)(t + 2) * RECS, r0, col);
        step(dCur, t);
        DecRec dNext = decode(rB);
        if (t + 3 < TB) rB = load_rec(Pb + (size_t)(t + 3) * RECS, r0, col);
        step(dNext, t + 1);
        dCur = decode(rA);
    }
}

// ---------------------------------------------------------------------------
// gated RMS norm: og = bf16( o*rsqrt(mean o^2+1e-5)*norm_w*sigmoid(gate+bg2) )
// ---------------------------------------------------------------------------
__global__ __launch_bounds__(256) void normgate_kernel(
    const ushort* __restrict__ o, const ushort* __restrict__ gate,
    const float* __restrict__ bg2, const float* __restrict__ norm_w,
    ushort* __restrict__ og) {
    const int lane = threadIdx.x & 63;
    const int wstart = (blockIdx.x * 256 + threadIdx.x) >> 6;
    const int nw = (gridDim.x * 256) >> 6;
    for (int pair = wstart; pair < TB * 16; pair += nw) {
        const int t = pair >> 4, h = pair & 15;
        const size_t basep = (size_t)t * 2048 + h * 128 + lane * 2;
        unsigned int ovu = *(const unsigned int*)(o + basep);
        float o0 = __uint_as_float(ovu << 16);
        float o1 = __uint_as_float(ovu & 0xffff0000u);
        float ss = o0 * o0 + o1 * o1;
#pragma unroll
        for (int m = 32; m >= 1; m >>= 1) ss += __shfl_xor(ss, m);
        float rn = rsqrtf(ss * (1.0f / 128.0f) + 1e-5f);
        const int dg = h * 128 + lane * 2;
        unsigned int gv = *(const unsigned int*)(gate + basep);
        float g0 = __uint_as_float(gv << 16) + bg2[dg];
        float g1 = __uint_as_float(gv & 0xffff0000u) + bg2[dg + 1];
        float w0 = norm_w[lane * 2], w1 = norm_w[lane * 2 + 1];
        float r0 = o0 * rn * w0 / (1.0f + expf(-g0));
        float r1 = o1 * rn * w1 / (1.0f + expf(-g1));
        unsigned int outw = (unsigned int)f2b(r0) | ((unsigned int)f2b(r1) << 16);
        *(unsigned int*)(og + basep) = outw;
    }
}

// ---------------------------------------------------------------------------
extern "C" void kernel_launch(void* const* d_in, const int* in_sizes, int n_in,
                              void* d_out, int out_size, void* d_ws, size_t ws_size,
                              hipStream_t stream) {
    const float* x = (const float*)d_in[0];
    const float* Wq = (const float*)d_in[1];
    const float* Wk = (const float*)d_in[2];
    const float* Wv = (const float*)d_in[3];
    const float* convq = (const float*)d_in[4];
    const float* convk = (const float*)d_in[5];
    const float* convv = (const float*)d_in[6];
    const float* A_log = (const float*)d_in[7];
    const float* dt_bias = (const float*)d_in[8];
    const float* Wsv = (const float*)d_in[9];
    const float* Wb1 = (const float*)d_in[10];
    const float* bb1 = (const float*)d_in[11];
    const float* Wb2 = (const float*)d_in[12];
    const float* bb2 = (const float*)d_in[13];
    const float* Wa1 = (const float*)d_in[14];
    const float* ba1 = (const float*)d_in[15];
    const float* Wa2 = (const float*)d_in[16];
    const float* ba2 = (const float*)d_in[17];
    const float* Wg1 = (const float*)d_in[18];
    const float* Wg2 = (const float*)d_in[19];
    const float* bg2 = (const float*)d_in[20];
    const float* norm_w = (const float*)d_in[21];
    const float* Wo = (const float*)d_in[22];

    // ---- workspace layout (bytes) ----
    const size_t OFF_WQKV = 0;                          // 25,165,824
    const size_t OFF_WG1  = OFF_WQKV + 25165824;        //    524,288
    const size_t OFF_WG2  = OFF_WG1 + 524288;           //    524,288
    const size_t OFF_WO   = OFF_WG2 + 524288;           //  8,388,608
    const size_t OFF_XB   = OFF_WO + 8388608;           // 16,777,216
    const size_t OFF_QKV  = OFF_XB + 16777216;          // 50,331,648
    const size_t OFF_P    = OFF_QKV + 50331648;         // per-batch 68,157,440
    const size_t PBYTES   = PSTRIDE * 2;                // 68,157,440
    // plan B: single-batch P + single-batch ob
    const size_t OFF_OB_B = OFF_P + PBYTES;
    const size_t OFF_XG1_B = OFF_OB_B + 16777216;
    const size_t NEED_B = OFF_XG1_B + 1048576;          // ~187.7 MB
    // plan A: both-batch P + both-batch ob
    const size_t OFF_OB_A = OFF_P + 2 * PBYTES;
    const size_t OFF_XG1_A = OFF_OB_A + 33554432;
    const size_t NEED_A = OFF_XG1_A + 1048576;          // ~272.6 MB
    if (ws_size < NEED_B) return;  // diagnostic guard
    const bool planA = (ws_size >= NEED_A);

    char* ws = (char*)d_ws;
    ushort* wqkv = (ushort*)(ws + OFF_WQKV);
    ushort* wg1b = (ushort*)(ws + OFF_WG1);
    ushort* wg2b = (ushort*)(ws + OFF_WG2);
    ushort* wob  = (ushort*)(ws + OFF_WO);
    ushort* xb   = (ushort*)(ws + OFF_XB);
    ushort* qkvb = (ushort*)(ws + OFF_QKV);
    ushort* P    = (ushort*)(ws + OFF_P);
    ushort* ob   = (ushort*)(ws + (planA ? OFF_OB_A : OFF_OB_B));
    ushort* xg1b = (ushort*)(ws + (planA ? OFF_XG1_A : OFF_XG1_B));
    // aliases into qkvb (dead after conv_stats):
    ushort* gateb = qkvb;
    ushort* ogb   = qkvb + 16777216;   // shorts offset -> +32MB? no: +16.7M shorts
    // NOTE: qkvb region is 50.3MB; gate (16.8MB) at +0, og (16.8MB) at +16.8MB.
    ogb = (ushort*)(ws + OFF_QKV + 16777216);

    // ---- weight casts ----
    cast_f32_bf16<<<512, 256, 0, stream>>>(Wq, wqkv, 4194304);
    cast_f32_bf16<<<512, 256, 0, stream>>>(Wk, wqkv + 4194304, 4194304);
    cast_f32_bf16<<<512, 256, 0, stream>>>(Wv, wqkv + 8388608, 4194304);
    cast_f32_bf16<<<64, 256, 0, stream>>>(Wg1, wg1b, 262144);
    cast_f32_bf16<<<64, 256, 0, stream>>>(Wg2, wg2b, 262144);
    cast_f32_bf16<<<512, 256, 0, stream>>>(Wo, wob, 4194304);

    if (planA) {
        // phase 1: produce P for both batches
        for (int b = 0; b < 2; ++b) {
            cast_f32_bf16<<<512, 256, 0, stream>>>(x + (size_t)b * TB * 2048, xb, TB * 2048);
            gemm_bf16<ushort><<<dim3(48, TB / 128), 256, 0, stream>>>(xb, wqkv, qkvb, TB, 6144, 2048);
            conv_stats_kernel<<<TB * 16 / 8, 256, 0, stream>>>(qkvb, convq, convk, convv, Wsv,
                Wb1, bb1, Wb2, bb2, Wa1, ba1, Wa2, ba2, A_log, dt_bias, P + (size_t)b * PSTRIDE);
        }
        // phase 2: one scan over both batches
        scan_kernel<<<256, 256, 0, stream>>>(P, ob);
        // phase 3: gates + norm + output per batch
        for (int b = 0; b < 2; ++b) {
            cast_f32_bf16<<<512, 256, 0, stream>>>(x + (size_t)b * TB * 2048, xb, TB * 2048);
            gemm_bf16<ushort><<<dim3(1, TB / 128), 256, 0, stream>>>(xb, wg1b, xg1b, TB, 128, 2048);
            gemm_bf16<ushort><<<dim3(16, TB / 128), 256, 0, stream>>>(xg1b, wg2b, gateb, TB, 2048, 128);
            normgate_kernel<<<2048, 256, 0, stream>>>(ob + (size_t)b * TB * 2048, gateb, bg2, norm_w, ogb);
            gemm_bf16<float><<<dim3(16, TB / 128), 256, 0, stream>>>(ogb, wob,
                (float*)d_out + (size_t)b * TB * 2048, TB, 2048, 2048);
        }
    } else {
        for (int b = 0; b < 2; ++b) {
            cast_f32_bf16<<<512, 256, 0, stream>>>(x + (size_t)b * TB * 2048, xb, TB * 2048);
            gemm_bf16<ushort><<<dim3(48, TB / 128), 256, 0, stream>>>(xb, wqkv, qkvb, TB, 6144, 2048);
            conv_stats_kernel<<<TB * 16 / 8, 256, 0, stream>>>(qkvb, convq, convk, convv, Wsv,
                Wb1, bb1, Wb2, bb2, Wa1, ba1, Wa2, ba2, A_log, dt_bias, P);
            scan_kernel<<<128, 256, 0, stream>>>(P, ob);
            gemm_bf16<ushort><<<dim3(1, TB / 128), 256, 0, stream>>>(xb, wg1b, xg1b, TB, 128, 2048);
            gemm_bf16<ushort><<<dim3(16, TB / 128), 256, 0, stream>>>(xg1b, wg2b, gateb, TB, 2048, 128);
            normgate_kernel<<<2048, 256, 0, stream>>>(ob, gateb, bg2, norm_w, ogb);
            gemm_bf16<float><<<dim3(16, TB / 128), 256, 0, stream>>>(ogb, wob,
                (float*)d_out + (size_t)b * TB * 2048, TB, 2048, 2048);
        }
    }
}

// Round 5
// 4283.972 us; speedup vs baseline: 1.4327x; 1.2422x over previous
//
#include <hip/hip_runtime.h>
#include <hip/hip_bf16.h>

// ---------------------------------------------------------------------------
// SurpriseKimiDeltaAttention  (B=2, T=4096, H=2048, NH=16, DK=DV=128, CONV=4)
// Per-batch pipeline (planB only, ~180.4 MB workspace):
//   cast x -> qkv GEMM -> conv/stats -> gate GEMMs -> cast Wo -> prepass
//   -> scan (register-pipelined, D=5 deferral) -> normgate -> out GEMM
// Record (per h,t; 664 shorts = 1328 B), index r = t+4 (recs 0..3 zero pads):
//   bytes: kw@0 qw@256 k@512 E@768 v@1024 sc@1280 (f32[12]: beta,qk,a1..4,qb1..4)
// Scan recurrence (deferral D=5):
//   pk_t = kw_t . S_{t-5} + sum_m a_m(t) d_{t-m};  d_t = beta (v_t - pk_t)
//   o_t  = qw_t . S_{t-5} + sum_m qb_m d_{t-m} + qk d_t
//   S_t  = E_t * S_{t-1} + k_t d_t   (raw k,E)
// ---------------------------------------------------------------------------

typedef __attribute__((ext_vector_type(8))) short bf16x8;
typedef __attribute__((ext_vector_type(4))) float floatx4;

#define TB 4096
#define RSH 664                      // shorts per record
#define RB 1328                      // bytes per record
#define NREC 4100                    // 4 zero pads + TB
#define BHSH ((size_t)NREC * RSH)    // shorts per (h) stream (one batch)

__device__ __forceinline__ float b2f(ushort u) {
    union { unsigned int u; float f; } c; c.u = ((unsigned int)u) << 16; return c.f;
}
__device__ __forceinline__ ushort f2b(float f) {
    union { float f; unsigned int u; } c; c.f = f;
    unsigned int r = (c.u + 0x7fffu + ((c.u >> 16) & 1u)) >> 16;
    return (ushort)r;
}
__device__ __forceinline__ float silu(float x) { return x / (1.0f + expf(-x)); }

// ---------------------------------------------------------------------------
__global__ __launch_bounds__(256) void cast_f32_bf16(const float* __restrict__ in,
                                                     ushort* __restrict__ out, int n) {
    int i = (blockIdx.x * 256 + threadIdx.x) * 4;
    int stride = gridDim.x * 256 * 4;
    for (; i + 3 < n; i += stride) {
        float4 v = *(const float4*)(in + i);
        ushort4 u;
        u.x = f2b(v.x); u.y = f2b(v.y); u.z = f2b(v.z); u.w = f2b(v.w);
        *(ushort4*)(out + i) = u;
    }
}

// ---------------------------------------------------------------------------
// bf16 MFMA GEMM: C[M][N] = A[M][K] @ B[N][K]^T  (row-major, K contiguous)
// ---------------------------------------------------------------------------
template <typename CT>
__global__ __launch_bounds__(256) void gemm_bf16(const ushort* __restrict__ A,
                                                 const ushort* __restrict__ B,
                                                 CT* __restrict__ C, int M, int N, int K) {
    __shared__ ushort As[128 * 40];
    __shared__ ushort Bs[128 * 40];
    const int tid = threadIdx.x;
    const int lane = tid & 63, wid = tid >> 6;
    const int wr = wid >> 1, wc = wid & 1;
    const int bm = blockIdx.y, bn = blockIdx.x;

    const int r0 = tid >> 2;
    const int kc0 = (tid & 3) * 8;
    const size_t aoff0 = (size_t)(bm * 128 + r0) * K + kc0;
    const size_t aoff1 = aoff0 + (size_t)64 * K;
    const size_t boff0 = (size_t)(bn * 128 + r0) * K + kc0;
    const size_t boff1 = boff0 + (size_t)64 * K;
    const int lw0 = r0 * 40 + kc0;
    const int lw1 = (r0 + 64) * 40 + kc0;

    const int arow = wr * 64 + (lane & 15);
    const int brow = wc * 64 + (lane & 15);
    const int kg = (lane >> 4) * 8;

    floatx4 acc[4][4];
#pragma unroll
    for (int m = 0; m < 4; ++m)
#pragma unroll
        for (int n = 0; n < 4; ++n) acc[m][n] = (floatx4){0.f, 0.f, 0.f, 0.f};

    uint4 ra0 = *(const uint4*)(A + aoff0);
    uint4 ra1 = *(const uint4*)(A + aoff1);
    uint4 rb0 = *(const uint4*)(B + boff0);
    uint4 rb1 = *(const uint4*)(B + boff1);

    for (int kt = 32; kt <= K; kt += 32) {
        __syncthreads();
        *(uint4*)(As + lw0) = ra0;
        *(uint4*)(As + lw1) = ra1;
        *(uint4*)(Bs + lw0) = rb0;
        *(uint4*)(Bs + lw1) = rb1;
        __syncthreads();
        if (kt < K) {
            ra0 = *(const uint4*)(A + aoff0 + kt);
            ra1 = *(const uint4*)(A + aoff1 + kt);
            rb0 = *(const uint4*)(B + boff0 + kt);
            rb1 = *(const uint4*)(B + boff1 + kt);
        }
        bf16x8 af[4], bfr[4];
#pragma unroll
        for (int m = 0; m < 4; ++m) af[m] = *(const bf16x8*)(As + (arow + m * 16) * 40 + kg);
#pragma unroll
        for (int n = 0; n < 4; ++n) bfr[n] = *(const bf16x8*)(Bs + (brow + n * 16) * 40 + kg);
#pragma unroll
        for (int m = 0; m < 4; ++m)
#pragma unroll
            for (int n = 0; n < 4; ++n)
                acc[m][n] = __builtin_amdgcn_mfma_f32_16x16x32_bf16(af[m], bfr[n], acc[m][n], 0, 0, 0);
    }

    const int crow0 = bm * 128 + wr * 64 + (lane >> 4) * 4;
    const int ccol0 = bn * 128 + wc * 64 + (lane & 15);
#pragma unroll
    for (int m = 0; m < 4; ++m)
#pragma unroll
        for (int n = 0; n < 4; ++n)
#pragma unroll
            for (int j = 0; j < 4; ++j) {
                int row = crow0 + m * 16 + j;
                int col = ccol0 + n * 16;
                if constexpr (sizeof(CT) == 2)
                    C[(size_t)row * N + col] = (CT)f2b(acc[m][n][j]);
                else
                    C[(size_t)row * N + col] = (CT)acc[m][n][j];
            }
}

// ---------------------------------------------------------------------------
// conv + silu + surprise stats + beta/amp MLPs -> record fields (one batch)
// ---------------------------------------------------------------------------
__global__ __launch_bounds__(256) void conv_stats_kernel(
    const ushort* __restrict__ qkv,
    const float* __restrict__ convq, const float* __restrict__ convk,
    const float* __restrict__ convv, const float* __restrict__ Wsv,
    const float* __restrict__ Wb1, const float* __restrict__ bb1,
    const float* __restrict__ Wb2, const float* __restrict__ bb2,
    const float* __restrict__ Wa1, const float* __restrict__ ba1,
    const float* __restrict__ Wa2, const float* __restrict__ ba2,
    const float* __restrict__ A_log, const float* __restrict__ dt_bias,
    ushort* __restrict__ P) {
    __shared__ ushort wsv_s[128 * 136];
    __shared__ float k_sh[4][128];
    // zero-fill pad records 0..3 for each h
    if (blockIdx.x == 0) {
        for (int z = threadIdx.x; z < 16 * 4 * RSH; z += 256) {
            int hh = z / (4 * RSH);
            int off = z % (4 * RSH);
            P[(size_t)hh * BHSH + off] = 0;
        }
    }
    for (int i = threadIdx.x; i < 128 * 128; i += 256) {
        int row = i >> 7, col = i & 127;
        wsv_s[row * 136 + col] = f2b(Wsv[i]);
    }
    __syncthreads();
    const int wid = threadIdx.x >> 6, lane = threadIdx.x & 63;

    for (int it = 0; it < 2; ++it) {
        const int pair = blockIdx.x * 8 + it * 4 + wid;   // [0, TB*16)
        const int t = pair >> 4, h = pair & 15;
        const int c0 = h * 128 + lane, c1 = c0 + 64;

        float wq[4], wq2[4], wk[4], wk2[4], wv[4], wv2[4];
#pragma unroll
        for (int i2 = 0; i2 < 4; ++i2) {
            wq[i2] = convq[c0 * 4 + i2]; wq2[i2] = convq[c1 * 4 + i2];
            wk[i2] = convk[c0 * 4 + i2]; wk2[i2] = convk[c1 * 4 + i2];
            wv[i2] = convv[c0 * 4 + i2]; wv2[i2] = convv[c1 * 4 + i2];
        }
        float aq0 = 0, aq1 = 0, ak0 = 0, ak1 = 0, av0 = 0, av1 = 0;
#pragma unroll
        for (int i2 = 0; i2 < 4; ++i2) {
            int tt = t - 3 + i2;
            if (tt >= 0) {
                const ushort* rowp = qkv + (size_t)tt * 6144 + h * 128;
                aq0 = fmaf(b2f(rowp[lane]), wq[i2], aq0);
                aq1 = fmaf(b2f(rowp[lane + 64]), wq2[i2], aq1);
                ak0 = fmaf(b2f(rowp[2048 + lane]), wk[i2], ak0);
                ak1 = fmaf(b2f(rowp[2048 + lane + 64]), wk2[i2], ak1);
                av0 = fmaf(b2f(rowp[4096 + lane]), wv[i2], av0);
                av1 = fmaf(b2f(rowp[4096 + lane + 64]), wv2[i2], av1);
            }
        }
        float q0 = silu(aq0), q1 = silu(aq1);
        float k0 = silu(ak0), k1 = silu(ak1);
        float v0 = silu(av0), v1 = silu(av1);

        __syncthreads();
        k_sh[wid][lane] = k0;
        k_sh[wid][lane + 64] = k1;
        __syncthreads();

        float vh0 = 0.f, vh1 = 0.f;
        const ushort* wr0 = wsv_s + lane * 136;
        const ushort* wr1 = wsv_s + (lane + 64) * 136;
#pragma unroll 4
        for (int j = 0; j < 128; j += 8) {
            float4 ka = *(const float4*)&k_sh[wid][j];
            float4 kb = *(const float4*)&k_sh[wid][j + 4];
            uint4 wa = *(const uint4*)(wr0 + j);
            uint4 wb = *(const uint4*)(wr1 + j);
            vh0 = fmaf(__uint_as_float(wa.x << 16), ka.x, vh0);
            vh0 = fmaf(__uint_as_float(wa.x & 0xffff0000u), ka.y, vh0);
            vh0 = fmaf(__uint_as_float(wa.y << 16), ka.z, vh0);
            vh0 = fmaf(__uint_as_float(wa.y & 0xffff0000u), ka.w, vh0);
            vh0 = fmaf(__uint_as_float(wa.z << 16), kb.x, vh0);
            vh0 = fmaf(__uint_as_float(wa.z & 0xffff0000u), kb.y, vh0);
            vh0 = fmaf(__uint_as_float(wa.w << 16), kb.z, vh0);
            vh0 = fmaf(__uint_as_float(wa.w & 0xffff0000u), kb.w, vh0);
            vh1 = fmaf(__uint_as_float(wb.x << 16), ka.x, vh1);
            vh1 = fmaf(__uint_as_float(wb.x & 0xffff0000u), ka.y, vh1);
            vh1 = fmaf(__uint_as_float(wb.y << 16), ka.z, vh1);
            vh1 = fmaf(__uint_as_float(wb.y & 0xffff0000u), ka.w, vh1);
            vh1 = fmaf(__uint_as_float(wb.z << 16), kb.x, vh1);
            vh1 = fmaf(__uint_as_float(wb.z & 0xffff0000u), kb.y, vh1);
            vh1 = fmaf(__uint_as_float(wb.w << 16), kb.z, vh1);
            vh1 = fmaf(__uint_as_float(wb.w & 0xffff0000u), kb.w, vh1);
        }

        float e0 = vh0 - v0, e1 = vh1 - v1;
        float se2 = e0 * e0 + e1 * e1;
        float sl1 = fabsf(e0) + fabsf(e1);
        float shv = vh0 * v0 + vh1 * v1;
        float shh = vh0 * vh0 + vh1 * vh1;
        float svv = v0 * v0 + v1 * v1;
        float sk2 = k0 * k0 + k1 * k1;
        float sq2 = q0 * q0 + q1 * q1;
#pragma unroll
        for (int m = 32; m >= 1; m >>= 1) {
            se2 += __shfl_xor(se2, m);
            sl1 += __shfl_xor(sl1, m);
            shv += __shfl_xor(shv, m);
            shh += __shfl_xor(shh, m);
            svv += __shfl_xor(svv, m);
            sk2 += __shfl_xor(sk2, m);
            sq2 += __shfl_xor(sq2, m);
        }
        float s_l2 = sqrtf(se2 + 1e-6f);
        float s_l1 = sl1;
        float s_cos = 1.0f - shv / (sqrtf(shh + 1e-6f) * sqrtf(svv + 1e-6f) + 1e-6f);

        const int j2 = lane & 31;
        const float* W1 = (lane < 32) ? Wb1 : Wa1;
        const float* b1 = (lane < 32) ? bb1 : ba1;
        const float* W2 = (lane < 32) ? Wb2 : Wa2;
        float pre = W1[j2 * 3] * s_l2 + W1[j2 * 3 + 1] * s_l1 + W1[j2 * 3 + 2] * s_cos + b1[j2];
        float val = W2[j2] * silu(pre);
#pragma unroll
        for (int m = 16; m >= 1; m >>= 1) val += __shfl_xor(val, m);
        float pre_b = __shfl(val, 0) + bb2[0];
        float pre_a = __shfl(val, 32) + ba2[0];
        float betav = 1.0f / (1.0f + expf(-pre_b));
        float amp = pre_a;

        float knorm = sqrtf(sk2);
        float rinv = amp / fmaxf(knorm, 1e-12f);
        float ah = expf(A_log[h]);
        float gr0 = fmaf(k0, rinv, dt_bias[c0]);
        float gr1 = fmaf(k1, rinv, dt_bias[c1]);
        float sp0 = (gr0 > 20.f) ? gr0 : log1pf(expf(gr0));
        float sp1 = (gr1 > 20.f) ? gr1 : log1pf(expf(gr1));

        ushort* rec = P + (size_t)h * BHSH + (size_t)(t + 4) * RSH;
        float kinv = rsqrtf(sk2 + 1e-6f);
        float qinv = rsqrtf(sq2 + 1e-6f) * 0.08838834764831845f;  // * DK^-0.5
        rec[128 + lane]      = f2b(q0 * qinv);     // q~ (prepass overwrites with qw)
        rec[128 + lane + 64] = f2b(q1 * qinv);
        rec[256 + lane]      = f2b(k0 * kinv);     // raw normalized k
        rec[256 + lane + 64] = f2b(k1 * kinv);
        rec[384 + lane]      = f2b(expf(-ah * sp0));  // E = exp(g)
        rec[384 + lane + 64] = f2b(expf(-ah * sp1));
        rec[512 + lane]      = f2b(v0);
        rec[512 + lane + 64] = f2b(v1);
        if (lane == 0) *(float*)(rec + 640) = betav;
    }
}

// ---------------------------------------------------------------------------
// prepass: kw = k*W5, qw = q~*W5 (W5 = prod_{i=0..4} E_{t-i}), scalars
// qk, a1..a4, qb1..qb4.  One wave per record; in-place.
// ---------------------------------------------------------------------------
__global__ __launch_bounds__(256) void prepass_kernel(ushort* __restrict__ P) {
    const int g = blockIdx.x * 4 + (threadIdx.x >> 6);
    const int bh = g >> 12, t = g & 4095;
    const int lane = threadIdx.x & 63;
    ushort* rec = P + (size_t)bh * BHSH + (size_t)(t + 4) * RSH;

    float kt0 = b2f(rec[256 + lane]), kt1 = b2f(rec[256 + lane + 64]);
    float qt0 = b2f(rec[128 + lane]), qt1 = b2f(rec[128 + lane + 64]);
    float a[4], qb[4];
    float wa = b2f(rec[384 + lane]), wb = b2f(rec[384 + lane + 64]);  // E_t
    float qk = qt0 * kt0 + qt1 * kt1;
#pragma unroll
    for (int m = 1; m <= 4; ++m) {
        const ushort* rp = rec - (size_t)m * RSH;
        float kp0 = b2f(rp[256 + lane]), kp1 = b2f(rp[256 + lane + 64]);
        a[m - 1]  = kt0 * wa * kp0 + kt1 * wb * kp1;
        qb[m - 1] = qt0 * wa * kp0 + qt1 * wb * kp1;
        float ep0 = b2f(rp[384 + lane]), ep1 = b2f(rp[384 + lane + 64]);
        wa *= ep0; wb *= ep1;   // after loop: wa = W5 per dim
    }
#pragma unroll
    for (int m = 32; m >= 1; m >>= 1) {
        qk += __shfl_xor(qk, m);
        a[0] += __shfl_xor(a[0], m); a[1] += __shfl_xor(a[1], m);
        a[2] += __shfl_xor(a[2], m); a[3] += __shfl_xor(a[3], m);
        qb[0] += __shfl_xor(qb[0], m); qb[1] += __shfl_xor(qb[1], m);
        qb[2] += __shfl_xor(qb[2], m); qb[3] += __shfl_xor(qb[3], m);
    }
    rec[lane]            = f2b(kt0 * wa);
    rec[lane + 64]       = f2b(kt1 * wb);
    rec[128 + lane]      = f2b(qt0 * wa);
    rec[128 + lane + 64] = f2b(qt1 * wb);
    if (lane == 0) {
        float* sc = (float*)(rec + 640);
        sc[1] = qk;
        sc[2] = a[0]; sc[3] = a[1]; sc[4] = a[2]; sc[5] = a[3];
        sc[6] = qb[0]; sc[7] = qb[1]; sc[8] = qb[2]; sc[9] = qb[3];
    }
}

// ---------------------------------------------------------------------------
// scan: register-pipelined, one batch.  128 blocks x 256 thr.
// block = 16 colgroups x 16 lanes; thread: 8 dims x 1 col.
// 3-stage rotation A/B/C: stage consumed at body J was loaded at body J-3.
// ---------------------------------------------------------------------------
struct Stage {
    uint4 kek, kee, kqw, kqq;
    uint vv;
    float4 s0, s1;
    float2 s2;
};

__device__ __forceinline__ void dec8(uint4 u, float* f) {
    f[0] = __uint_as_float(u.x << 16); f[1] = __uint_as_float(u.x & 0xffff0000u);
    f[2] = __uint_as_float(u.y << 16); f[3] = __uint_as_float(u.y & 0xffff0000u);
    f[4] = __uint_as_float(u.z << 16); f[5] = __uint_as_float(u.z & 0xffff0000u);
    f[6] = __uint_as_float(u.w << 16); f[7] = __uint_as_float(u.w & 0xffff0000u);
}

__global__ __launch_bounds__(256) void scan_kernel(const ushort* __restrict__ P,
                                                   ushort* __restrict__ ob) {
    const int tid = threadIdx.x;
    const int l16 = tid & 15, cg = tid >> 4;
    const int h = blockIdx.x >> 3, blk = blockIdx.x & 7;
    const int col = blk * 16 + cg;
    const char* gb = (const char*)(P + (size_t)h * BHSH);
    ushort* op = ob + h * 128 + col;
    const int lo = l16 * 16;

    auto ld = [&](Stage& st, int rke, int rkq, int rvs) {
        const char* pa = gb + (size_t)rke * RB;
        const char* pb = gb + (size_t)rkq * RB;
        const char* pc = gb + (size_t)rvs * RB;
        st.kek = *(const uint4*)(pa + 512 + lo);
        st.kee = *(const uint4*)(pa + 768 + lo);
        st.kqw = *(const uint4*)(pb + 0 + lo);
        st.kqq = *(const uint4*)(pb + 256 + lo);
        st.vv  = *(const ushort*)(pc + 1024 + col * 2);
        st.s0  = *(const float4*)(pc + 1280);
        st.s1  = *(const float4*)(pc + 1296);
        st.s2  = *(const float2*)(pc + 1312);
    };

    Stage A, B, C;
    ld(A, 0, 5, 2); ld(B, 1, 6, 3); ld(C, 2, 7, 4);

    float S[8];
#pragma unroll
    for (int i = 0; i < 8; ++i) S[i] = 0.f;
    float d1 = 0.f, d2 = 0.f, d3 = 0.f, d4 = 0.f;
    float Ap = 0.f, Aq = 0.f, Bp = 0.f, Bq = 0.f, Cp = 0.f, Cq = 0.f;

    auto body = [&](int J, Stage& st) {
        float k8[8], e8[8], w8[8], q8[8];
        dec8(st.kek, k8); dec8(st.kee, e8);
        dec8(st.kqw, w8); dec8(st.kqq, q8);
        float vj = b2f((ushort)st.vv);
        float beta = st.s0.x, qk = st.s0.y;
        float a1 = st.s0.z, a2 = st.s0.w, a3 = st.s1.x, a4 = st.s1.y;
        float qb1 = st.s1.z, qb2 = st.s1.w, qb3 = st.s2.x, qb4 = st.s2.y;
        // refill (consumed again 3 bodies later)
        {
            int rke = J + 5;  if (rke > NREC - 1) rke = NREC - 1;
            int rkq = J + 10; if (rkq > NREC - 1) rkq = NREC - 1;
            int rvs = J + 7;  if (rvs > NREC - 1) rvs = NREC - 1;
            ld(st, rke, rkq, rvs);
        }
        // S update: t = J-2  (S becomes S_{J-2})
#pragma unroll
        for (int i = 0; i < 8; ++i) S[i] = fmaf(k8[i], d2, e8[i] * S[i]);
        // dots for t = J+3  (kw_{J+3} . S_{J-2})
        float pk = 0.f, pq = 0.f;
#pragma unroll
        for (int i = 0; i < 8; ++i) { pk = fmaf(w8[i], S[i], pk); pq = fmaf(q8[i], S[i], pq); }
        // scalar chain: t = J
        float pks = Cp + a1 * d1 + a2 * d2 + a3 * d3 + a4 * d4;
        float dl = beta * (vj - pks);
        float oo = Cq + qb1 * d1 + qb2 * d2 + qb3 * d3 + qb4 * d4 + qk * dl;
        if (J >= 0 && l16 == 0) op[(size_t)J * 2048] = f2b(oo);
        // reduction pipeline rotate (4 shfl levels spread over 3 bodies)
        float tp = Bp + __shfl_xor(Bp, 4); Cp = tp + __shfl_xor(tp, 8);
        float tq = Bq + __shfl_xor(Bq, 4); Cq = tq + __shfl_xor(tq, 8);
        Bp = Ap + __shfl_xor(Ap, 2); Bq = Aq + __shfl_xor(Aq, 2);
        Ap = pk + __shfl_xor(pk, 1); Aq = pq + __shfl_xor(pq, 1);
        d4 = d3; d3 = d2; d2 = d1; d1 = dl;
    };

    int J = -2;
    for (int it = 0; it < 1366; ++it) {   // 1366*3 = 4098 bodies: J = -2 .. 4095
        body(J, A);
        body(J + 1, B);
        body(J + 2, C);
        J += 3;
    }
}

// ---------------------------------------------------------------------------
// gated RMS norm: og = bf16( o*rsqrt(mean o^2+1e-5)*norm_w*sigmoid(gate+bg2) )
// ---------------------------------------------------------------------------
__global__ __launch_bounds__(256) void normgate_kernel(
    const ushort* __restrict__ o, const ushort* __restrict__ gate,
    const float* __restrict__ bg2, const float* __restrict__ norm_w,
    ushort* __restrict__ og) {
    const int lane = threadIdx.x & 63;
    const int wstart = (blockIdx.x * 256 + threadIdx.x) >> 6;
    const int nw = (gridDim.x * 256) >> 6;
    for (int pair = wstart; pair < TB * 16; pair += nw) {
        const int t = pair >> 4, h = pair & 15;
        const size_t basep = (size_t)t * 2048 + h * 128 + lane * 2;
        unsigned int ovu = *(const unsigned int*)(o + basep);
        float o0 = __uint_as_float(ovu << 16);
        float o1 = __uint_as_float(ovu & 0xffff0000u);
        float ss = o0 * o0 + o1 * o1;
#pragma unroll
        for (int m = 32; m >= 1; m >>= 1) ss += __shfl_xor(ss, m);
        float rn = rsqrtf(ss * (1.0f / 128.0f) + 1e-5f);
        const int dg = h * 128 + lane * 2;
        unsigned int gv = *(const unsigned int*)(gate + basep);
        float g0 = __uint_as_float(gv << 16) + bg2[dg];
        float g1 = __uint_as_float(gv & 0xffff0000u) + bg2[dg + 1];
        float w0 = norm_w[lane * 2], w1 = norm_w[lane * 2 + 1];
        float r0 = o0 * rn * w0 / (1.0f + expf(-g0));
        float r1 = o1 * rn * w1 / (1.0f + expf(-g1));
        unsigned int outw = (unsigned int)f2b(r0) | ((unsigned int)f2b(r1) << 16);
        *(unsigned int*)(og + basep) = outw;
    }
}

// ---------------------------------------------------------------------------
extern "C" void kernel_launch(void* const* d_in, const int* in_sizes, int n_in,
                              void* d_out, int out_size, void* d_ws, size_t ws_size,
                              hipStream_t stream) {
    const float* x = (const float*)d_in[0];
    const float* Wq = (const float*)d_in[1];
    const float* Wk = (const float*)d_in[2];
    const float* Wv = (const float*)d_in[3];
    const float* convq = (const float*)d_in[4];
    const float* convk = (const float*)d_in[5];
    const float* convv = (const float*)d_in[6];
    const float* A_log = (const float*)d_in[7];
    const float* dt_bias = (const float*)d_in[8];
    const float* Wsv = (const float*)d_in[9];
    const float* Wb1 = (const float*)d_in[10];
    const float* bb1 = (const float*)d_in[11];
    const float* Wb2 = (const float*)d_in[12];
    const float* bb2 = (const float*)d_in[13];
    const float* Wa1 = (const float*)d_in[14];
    const float* ba1 = (const float*)d_in[15];
    const float* Wa2 = (const float*)d_in[16];
    const float* ba2 = (const float*)d_in[17];
    const float* Wg1 = (const float*)d_in[18];
    const float* Wg2 = (const float*)d_in[19];
    const float* bg2 = (const float*)d_in[20];
    const float* norm_w = (const float*)d_in[21];
    const float* Wo = (const float*)d_in[22];

    // ---- workspace layout (planB only, bytes) ----
    const size_t OFF_WQKV = 0;                         // 25,165,824
    const size_t OFF_WG1  = OFF_WQKV + 25165824;       //    524,288
    const size_t OFF_WG2  = OFF_WG1 + 524288;          //    524,288
    const size_t OFF_XB   = OFF_WG2 + 524288;          // 16,777,216  (xb; later ob)
    const size_t OFF_QKV  = OFF_XB + 16777216;         // 50,331,648  (qkv; later gate|xg1|og|wob)
    const size_t OFF_P    = OFF_QKV + 50331648;        // 87,116,800
    const size_t NEED     = OFF_P + (size_t)16 * BHSH * 2;   // 180,440,064
    if (ws_size < NEED) return;  // diagnostic guard

    char* ws = (char*)d_ws;
    ushort* wqkv = (ushort*)(ws + OFF_WQKV);
    ushort* wg1b = (ushort*)(ws + OFF_WG1);
    ushort* wg2b = (ushort*)(ws + OFF_WG2);
    ushort* xb   = (ushort*)(ws + OFF_XB);
    ushort* qkvb = (ushort*)(ws + OFF_QKV);
    ushort* P    = (ushort*)(ws + OFF_P);
    // aliases (all live only after conv_stats frees the qkv region):
    ushort* gateb = qkvb;                               // +0        16,777,216
    ushort* xg1b  = (ushort*)(ws + OFF_QKV + 16777216); // +16.78M    1,048,576
    ushort* ogb   = (ushort*)(ws + OFF_QKV + 17825792); // +17.83M   16,777,216
    ushort* wob   = (ushort*)(ws + OFF_QKV + 34603008); // +34.60M    8,388,608
    ushort* obp   = xb;                                 // scan output (xb dead)

    // weight casts (persist across batches)
    cast_f32_bf16<<<512, 256, 0, stream>>>(Wq, wqkv, 4194304);
    cast_f32_bf16<<<512, 256, 0, stream>>>(Wk, wqkv + 4194304, 4194304);
    cast_f32_bf16<<<512, 256, 0, stream>>>(Wv, wqkv + 8388608, 4194304);
    cast_f32_bf16<<<64, 256, 0, stream>>>(Wg1, wg1b, 262144);
    cast_f32_bf16<<<64, 256, 0, stream>>>(Wg2, wg2b, 262144);

    for (int b = 0; b < 2; ++b) {
        const float* xbp = x + (size_t)b * TB * 2048;
        float* outp = (float*)d_out + (size_t)b * TB * 2048;

        cast_f32_bf16<<<512, 256, 0, stream>>>(xbp, xb, TB * 2048);
        gemm_bf16<ushort><<<dim3(48, TB / 128), 256, 0, stream>>>(xb, wqkv, qkvb, TB, 6144, 2048);
        conv_stats_kernel<<<TB * 16 / 8, 256, 0, stream>>>(qkvb, convq, convk, convv, Wsv,
            Wb1, bb1, Wb2, bb2, Wa1, ba1, Wa2, ba2, A_log, dt_bias, P);
        // qkv region now dead -> gate pipeline may reuse it
        gemm_bf16<ushort><<<dim3(1, TB / 128), 256, 0, stream>>>(xb, wg1b, xg1b, TB, 128, 2048);
        gemm_bf16<ushort><<<dim3(16, TB / 128), 256, 0, stream>>>(xg1b, wg2b, gateb, TB, 2048, 128);
        cast_f32_bf16<<<512, 256, 0, stream>>>(Wo, wob, 4194304);
        prepass_kernel<<<16 * 1024, 256, 0, stream>>>(P);
        // xb dead -> scan writes ob there
        scan_kernel<<<128, 256, 0, stream>>>(P, obp);
        normgate_kernel<<<2048, 256, 0, stream>>>(obp, gateb, bg2, norm_w, ogb);
        gemm_bf16<float><<<dim3(16, TB / 128), 256, 0, stream>>>(ogb, wob, outp, TB, 2048, 2048);
    }
}

// Round 6
// 2740.158 us; speedup vs baseline: 2.2399x; 1.5634x over previous
//
#include <hip/hip_runtime.h>
#include <hip/hip_bf16.h>

// ---------------------------------------------------------------------------
// SurpriseKimiDeltaAttention  (B=2, T=4096, H=2048, NH=16, DK=DV=128, CONV=4)
// Pipeline: cast -> qkv GEMM -> conv/stats -> gate GEMMs -> prepass ->
//           scan (reg-pipelined, D=5 deferral, 5-stage prefetch) ->
//           normgate -> out GEMM
// Record (per h,t; 664 shorts = 1328 B), index r = t+4 (recs 0..3 zero pads):
//   bytes: kw@0 qw@256 k@512 E@768 v@1024 sc@1280 (f32[12]: beta,qk,a1..4,qb1..4)
// Scan recurrence (deferral D=5):
//   pk_t = kw_t . S_{t-5} + sum_m a_m(t) d_{t-m};  d_t = beta (v_t - pk_t)
//   o_t  = qw_t . S_{t-5} + sum_m qb_m d_{t-m} + qk d_t
//   S_t  = E_t * S_{t-1} + k_t d_t
// Plan A (ws >= ~267.6MB): both batches' P resident -> ONE scan launch (256 blk).
// Plan B (ws >= ~180.4MB): per-batch sequential.
// ---------------------------------------------------------------------------

typedef __attribute__((ext_vector_type(8))) short bf16x8;
typedef __attribute__((ext_vector_type(4))) float floatx4;

#define TB 4096
#define RSH 664                      // shorts per record
#define RB 1328                      // bytes per record
#define NREC 4100                    // 4 zero pads + TB
#define BHSH ((size_t)NREC * RSH)    // shorts per (b,h) stream

__device__ __forceinline__ float b2f(ushort u) {
    union { unsigned int u; float f; } c; c.u = ((unsigned int)u) << 16; return c.f;
}
__device__ __forceinline__ ushort f2b(float f) {
    union { float f; unsigned int u; } c; c.f = f;
    unsigned int r = (c.u + 0x7fffu + ((c.u >> 16) & 1u)) >> 16;
    return (ushort)r;
}
__device__ __forceinline__ float silu(float x) { return x / (1.0f + expf(-x)); }

// ---------------------------------------------------------------------------
__global__ __launch_bounds__(256) void cast_f32_bf16(const float* __restrict__ in,
                                                     ushort* __restrict__ out, int n) {
    int i = (blockIdx.x * 256 + threadIdx.x) * 4;
    int stride = gridDim.x * 256 * 4;
    for (; i + 3 < n; i += stride) {
        float4 v = *(const float4*)(in + i);
        ushort4 u;
        u.x = f2b(v.x); u.y = f2b(v.y); u.z = f2b(v.z); u.w = f2b(v.w);
        *(ushort4*)(out + i) = u;
    }
}

// ---------------------------------------------------------------------------
// bf16 MFMA GEMM: C[M][N] = A[M][K] @ B[N][K]^T  (row-major, K contiguous)
// ---------------------------------------------------------------------------
template <typename CT>
__global__ __launch_bounds__(256) void gemm_bf16(const ushort* __restrict__ A,
                                                 const ushort* __restrict__ B,
                                                 CT* __restrict__ C, int M, int N, int K) {
    __shared__ ushort As[128 * 40];
    __shared__ ushort Bs[128 * 40];
    const int tid = threadIdx.x;
    const int lane = tid & 63, wid = tid >> 6;
    const int wr = wid >> 1, wc = wid & 1;
    const int bm = blockIdx.y, bn = blockIdx.x;

    const int r0 = tid >> 2;
    const int kc0 = (tid & 3) * 8;
    const size_t aoff0 = (size_t)(bm * 128 + r0) * K + kc0;
    const size_t aoff1 = aoff0 + (size_t)64 * K;
    const size_t boff0 = (size_t)(bn * 128 + r0) * K + kc0;
    const size_t boff1 = boff0 + (size_t)64 * K;
    const int lw0 = r0 * 40 + kc0;
    const int lw1 = (r0 + 64) * 40 + kc0;

    const int arow = wr * 64 + (lane & 15);
    const int brow = wc * 64 + (lane & 15);
    const int kg = (lane >> 4) * 8;

    floatx4 acc[4][4];
#pragma unroll
    for (int m = 0; m < 4; ++m)
#pragma unroll
        for (int n = 0; n < 4; ++n) acc[m][n] = (floatx4){0.f, 0.f, 0.f, 0.f};

    uint4 ra0 = *(const uint4*)(A + aoff0);
    uint4 ra1 = *(const uint4*)(A + aoff1);
    uint4 rb0 = *(const uint4*)(B + boff0);
    uint4 rb1 = *(const uint4*)(B + boff1);

    for (int kt = 32; kt <= K; kt += 32) {
        __syncthreads();
        *(uint4*)(As + lw0) = ra0;
        *(uint4*)(As + lw1) = ra1;
        *(uint4*)(Bs + lw0) = rb0;
        *(uint4*)(Bs + lw1) = rb1;
        __syncthreads();
        if (kt < K) {
            ra0 = *(const uint4*)(A + aoff0 + kt);
            ra1 = *(const uint4*)(A + aoff1 + kt);
            rb0 = *(const uint4*)(B + boff0 + kt);
            rb1 = *(const uint4*)(B + boff1 + kt);
        }
        bf16x8 af[4], bfr[4];
#pragma unroll
        for (int m = 0; m < 4; ++m) af[m] = *(const bf16x8*)(As + (arow + m * 16) * 40 + kg);
#pragma unroll
        for (int n = 0; n < 4; ++n) bfr[n] = *(const bf16x8*)(Bs + (brow + n * 16) * 40 + kg);
#pragma unroll
        for (int m = 0; m < 4; ++m)
#pragma unroll
            for (int n = 0; n < 4; ++n)
                acc[m][n] = __builtin_amdgcn_mfma_f32_16x16x32_bf16(af[m], bfr[n], acc[m][n], 0, 0, 0);
    }

    const int crow0 = bm * 128 + wr * 64 + (lane >> 4) * 4;
    const int ccol0 = bn * 128 + wc * 64 + (lane & 15);
#pragma unroll
    for (int m = 0; m < 4; ++m)
#pragma unroll
        for (int n = 0; n < 4; ++n)
#pragma unroll
            for (int j = 0; j < 4; ++j) {
                int row = crow0 + m * 16 + j;
                int col = ccol0 + n * 16;
                if constexpr (sizeof(CT) == 2)
                    C[(size_t)row * N + col] = (CT)f2b(acc[m][n][j]);
                else
                    C[(size_t)row * N + col] = (CT)acc[m][n][j];
            }
}

// ---------------------------------------------------------------------------
// conv + silu + surprise stats + beta/amp MLPs -> record fields (one batch)
// ---------------------------------------------------------------------------
__global__ __launch_bounds__(256) void conv_stats_kernel(
    const ushort* __restrict__ qkv,
    const float* __restrict__ convq, const float* __restrict__ convk,
    const float* __restrict__ convv, const float* __restrict__ Wsv,
    const float* __restrict__ Wb1, const float* __restrict__ bb1,
    const float* __restrict__ Wb2, const float* __restrict__ bb2,
    const float* __restrict__ Wa1, const float* __restrict__ ba1,
    const float* __restrict__ Wa2, const float* __restrict__ ba2,
    const float* __restrict__ A_log, const float* __restrict__ dt_bias,
    ushort* __restrict__ P) {
    __shared__ ushort wsv_s[128 * 136];
    __shared__ float k_sh[4][128];
    // zero-fill pad records 0..3 for each h
    if (blockIdx.x == 0) {
        for (int z = threadIdx.x; z < 16 * 4 * RSH; z += 256) {
            int hh = z / (4 * RSH);
            int off = z % (4 * RSH);
            P[(size_t)hh * BHSH + off] = 0;
        }
    }
    for (int i = threadIdx.x; i < 128 * 128; i += 256) {
        int row = i >> 7, col = i & 127;
        wsv_s[row * 136 + col] = f2b(Wsv[i]);
    }
    __syncthreads();
    const int wid = threadIdx.x >> 6, lane = threadIdx.x & 63;

    for (int it = 0; it < 2; ++it) {
        const int pair = blockIdx.x * 8 + it * 4 + wid;   // [0, TB*16)
        const int t = pair >> 4, h = pair & 15;
        const int c0 = h * 128 + lane, c1 = c0 + 64;

        float wq[4], wq2[4], wk[4], wk2[4], wv[4], wv2[4];
#pragma unroll
        for (int i2 = 0; i2 < 4; ++i2) {
            wq[i2] = convq[c0 * 4 + i2]; wq2[i2] = convq[c1 * 4 + i2];
            wk[i2] = convk[c0 * 4 + i2]; wk2[i2] = convk[c1 * 4 + i2];
            wv[i2] = convv[c0 * 4 + i2]; wv2[i2] = convv[c1 * 4 + i2];
        }
        float aq0 = 0, aq1 = 0, ak0 = 0, ak1 = 0, av0 = 0, av1 = 0;
#pragma unroll
        for (int i2 = 0; i2 < 4; ++i2) {
            int tt = t - 3 + i2;
            if (tt >= 0) {
                const ushort* rowp = qkv + (size_t)tt * 6144 + h * 128;
                aq0 = fmaf(b2f(rowp[lane]), wq[i2], aq0);
                aq1 = fmaf(b2f(rowp[lane + 64]), wq2[i2], aq1);
                ak0 = fmaf(b2f(rowp[2048 + lane]), wk[i2], ak0);
                ak1 = fmaf(b2f(rowp[2048 + lane + 64]), wk2[i2], ak1);
                av0 = fmaf(b2f(rowp[4096 + lane]), wv[i2], av0);
                av1 = fmaf(b2f(rowp[4096 + lane + 64]), wv2[i2], av1);
            }
        }
        float q0 = silu(aq0), q1 = silu(aq1);
        float k0 = silu(ak0), k1 = silu(ak1);
        float v0 = silu(av0), v1 = silu(av1);

        __syncthreads();
        k_sh[wid][lane] = k0;
        k_sh[wid][lane + 64] = k1;
        __syncthreads();

        float vh0 = 0.f, vh1 = 0.f;
        const ushort* wr0 = wsv_s + lane * 136;
        const ushort* wr1 = wsv_s + (lane + 64) * 136;
#pragma unroll 4
        for (int j = 0; j < 128; j += 8) {
            float4 ka = *(const float4*)&k_sh[wid][j];
            float4 kb = *(const float4*)&k_sh[wid][j + 4];
            uint4 wa = *(const uint4*)(wr0 + j);
            uint4 wb = *(const uint4*)(wr1 + j);
            vh0 = fmaf(__uint_as_float(wa.x << 16), ka.x, vh0);
            vh0 = fmaf(__uint_as_float(wa.x & 0xffff0000u), ka.y, vh0);
            vh0 = fmaf(__uint_as_float(wa.y << 16), ka.z, vh0);
            vh0 = fmaf(__uint_as_float(wa.y & 0xffff0000u), ka.w, vh0);
            vh0 = fmaf(__uint_as_float(wa.z << 16), kb.x, vh0);
            vh0 = fmaf(__uint_as_float(wa.z & 0xffff0000u), kb.y, vh0);
            vh0 = fmaf(__uint_as_float(wa.w << 16), kb.z, vh0);
            vh0 = fmaf(__uint_as_float(wa.w & 0xffff0000u), kb.w, vh0);
            vh1 = fmaf(__uint_as_float(wb.x << 16), ka.x, vh1);
            vh1 = fmaf(__uint_as_float(wb.x & 0xffff0000u), ka.y, vh1);
            vh1 = fmaf(__uint_as_float(wb.y << 16), ka.z, vh1);
            vh1 = fmaf(__uint_as_float(wb.y & 0xffff0000u), ka.w, vh1);
            vh1 = fmaf(__uint_as_float(wb.z << 16), kb.x, vh1);
            vh1 = fmaf(__uint_as_float(wb.z & 0xffff0000u), kb.y, vh1);
            vh1 = fmaf(__uint_as_float(wb.w << 16), kb.z, vh1);
            vh1 = fmaf(__uint_as_float(wb.w & 0xffff0000u), kb.w, vh1);
        }

        float e0 = vh0 - v0, e1 = vh1 - v1;
        float se2 = e0 * e0 + e1 * e1;
        float sl1 = fabsf(e0) + fabsf(e1);
        float shv = vh0 * v0 + vh1 * v1;
        float shh = vh0 * vh0 + vh1 * vh1;
        float svv = v0 * v0 + v1 * v1;
        float sk2 = k0 * k0 + k1 * k1;
        float sq2 = q0 * q0 + q1 * q1;
#pragma unroll
        for (int m = 32; m >= 1; m >>= 1) {
            se2 += __shfl_xor(se2, m);
            sl1 += __shfl_xor(sl1, m);
            shv += __shfl_xor(shv, m);
            shh += __shfl_xor(shh, m);
            svv += __shfl_xor(svv, m);
            sk2 += __shfl_xor(sk2, m);
            sq2 += __shfl_xor(sq2, m);
        }
        float s_l2 = sqrtf(se2 + 1e-6f);
        float s_l1 = sl1;
        float s_cos = 1.0f - shv / (sqrtf(shh + 1e-6f) * sqrtf(svv + 1e-6f) + 1e-6f);

        const int j2 = lane & 31;
        const float* W1 = (lane < 32) ? Wb1 : Wa1;
        const float* b1 = (lane < 32) ? bb1 : ba1;
        const float* W2 = (lane < 32) ? Wb2 : Wa2;
        float pre = W1[j2 * 3] * s_l2 + W1[j2 * 3 + 1] * s_l1 + W1[j2 * 3 + 2] * s_cos + b1[j2];
        float val = W2[j2] * silu(pre);
#pragma unroll
        for (int m = 16; m >= 1; m >>= 1) val += __shfl_xor(val, m);
        float pre_b = __shfl(val, 0) + bb2[0];
        float pre_a = __shfl(val, 32) + ba2[0];
        float betav = 1.0f / (1.0f + expf(-pre_b));
        float amp = pre_a;

        float knorm = sqrtf(sk2);
        float rinv = amp / fmaxf(knorm, 1e-12f);
        float ah = expf(A_log[h]);
        float gr0 = fmaf(k0, rinv, dt_bias[c0]);
        float gr1 = fmaf(k1, rinv, dt_bias[c1]);
        float sp0 = (gr0 > 20.f) ? gr0 : log1pf(expf(gr0));
        float sp1 = (gr1 > 20.f) ? gr1 : log1pf(expf(gr1));

        ushort* rec = P + (size_t)h * BHSH + (size_t)(t + 4) * RSH;
        float kinv = rsqrtf(sk2 + 1e-6f);
        float qinv = rsqrtf(sq2 + 1e-6f) * 0.08838834764831845f;  // * DK^-0.5
        rec[128 + lane]      = f2b(q0 * qinv);     // q~ (prepass overwrites with qw)
        rec[128 + lane + 64] = f2b(q1 * qinv);
        rec[256 + lane]      = f2b(k0 * kinv);     // raw normalized k
        rec[256 + lane + 64] = f2b(k1 * kinv);
        rec[384 + lane]      = f2b(expf(-ah * sp0));  // E = exp(g)
        rec[384 + lane + 64] = f2b(expf(-ah * sp1));
        rec[512 + lane]      = f2b(v0);
        rec[512 + lane + 64] = f2b(v1);
        if (lane == 0) *(float*)(rec + 640) = betav;
    }
}

// ---------------------------------------------------------------------------
// prepass: kw = k*W5, qw = q~*W5 (W5 = prod_{i=0..4} E_{t-i}), scalars
// qk, a1..a4, qb1..qb4.  One wave per record; in-place.
// ---------------------------------------------------------------------------
__global__ __launch_bounds__(256) void prepass_kernel(ushort* __restrict__ P) {
    const int g = blockIdx.x * 4 + (threadIdx.x >> 6);
    const int bh = g >> 12, t = g & 4095;
    const int lane = threadIdx.x & 63;
    ushort* rec = P + (size_t)bh * BHSH + (size_t)(t + 4) * RSH;

    float kt0 = b2f(rec[256 + lane]), kt1 = b2f(rec[256 + lane + 64]);
    float qt0 = b2f(rec[128 + lane]), qt1 = b2f(rec[128 + lane + 64]);
    float a[4], qb[4];
    float wa = b2f(rec[384 + lane]), wb = b2f(rec[384 + lane + 64]);  // E_t
    float qk = qt0 * kt0 + qt1 * kt1;
#pragma unroll
    for (int m = 1; m <= 4; ++m) {
        const ushort* rp = rec - (size_t)m * RSH;
        float kp0 = b2f(rp[256 + lane]), kp1 = b2f(rp[256 + lane + 64]);
        a[m - 1]  = kt0 * wa * kp0 + kt1 * wb * kp1;
        qb[m - 1] = qt0 * wa * kp0 + qt1 * wb * kp1;
        float ep0 = b2f(rp[384 + lane]), ep1 = b2f(rp[384 + lane + 64]);
        wa *= ep0; wb *= ep1;   // after loop: wa = W5 per dim
    }
#pragma unroll
    for (int m = 32; m >= 1; m >>= 1) {
        qk += __shfl_xor(qk, m);
        a[0] += __shfl_xor(a[0], m); a[1] += __shfl_xor(a[1], m);
        a[2] += __shfl_xor(a[2], m); a[3] += __shfl_xor(a[3], m);
        qb[0] += __shfl_xor(qb[0], m); qb[1] += __shfl_xor(qb[1], m);
        qb[2] += __shfl_xor(qb[2], m); qb[3] += __shfl_xor(qb[3], m);
    }
    rec[lane]            = f2b(kt0 * wa);
    rec[lane + 64]       = f2b(kt1 * wb);
    rec[128 + lane]      = f2b(qt0 * wa);
    rec[128 + lane + 64] = f2b(qt1 * wb);
    if (lane == 0) {
        float* sc = (float*)(rec + 640);
        sc[1] = qk;
        sc[2] = a[0]; sc[3] = a[1]; sc[4] = a[2]; sc[5] = a[3];
        sc[6] = qb[0]; sc[7] = qb[1]; sc[8] = qb[2]; sc[9] = qb[3];
    }
}

// ---------------------------------------------------------------------------
// scan: register-pipelined, 5-stage prefetch (distance 5) with compiler
// memory barriers to prevent load sinking.  grid = nb*128 blocks.
// block = 16 colgroups x 16 lanes; thread: 8 dims x 1 col.
// ---------------------------------------------------------------------------
struct Stage {
    uint4 kek, kee, kqw, kqq;
    uint vv;
    float4 s0, s1;
    float2 s2;
};

__device__ __forceinline__ void dec8(uint4 u, float* f) {
    f[0] = __uint_as_float(u.x << 16); f[1] = __uint_as_float(u.x & 0xffff0000u);
    f[2] = __uint_as_float(u.y << 16); f[3] = __uint_as_float(u.y & 0xffff0000u);
    f[4] = __uint_as_float(u.z << 16); f[5] = __uint_as_float(u.z & 0xffff0000u);
    f[6] = __uint_as_float(u.w << 16); f[7] = __uint_as_float(u.w & 0xffff0000u);
}

__global__ __launch_bounds__(256) void scan_kernel(const ushort* __restrict__ P,
                                                   ushort* __restrict__ ob) {
    const int tid = threadIdx.x;
    const int l16 = tid & 15, cg = tid >> 4;
    const int b = blockIdx.x >> 7;
    const int h = (blockIdx.x >> 3) & 15;
    const int blk = blockIdx.x & 7;
    const int col = blk * 16 + cg;
    const char* gb = (const char*)(P + (size_t)(b * 16 + h) * BHSH);
    ushort* op = ob + (size_t)b * TB * 2048 + h * 128 + col;
    const int lo = l16 * 16;

    auto ld = [&](Stage& st, int rke, int rkq, int rvs) {
        const char* pa = gb + (size_t)rke * RB;
        const char* pb = gb + (size_t)rkq * RB;
        const char* pc = gb + (size_t)rvs * RB;
        st.kek = *(const uint4*)(pa + 512 + lo);
        st.kee = *(const uint4*)(pa + 768 + lo);
        st.kqw = *(const uint4*)(pb + 0 + lo);
        st.kqq = *(const uint4*)(pb + 256 + lo);
        st.vv  = *(const ushort*)(pc + 1024 + col * 2);
        st.s0  = *(const float4*)(pc + 1280);
        st.s1  = *(const float4*)(pc + 1296);
        st.s2  = *(const float2*)(pc + 1312);
    };

    Stage A, B, C, D, E5;
    ld(A, 0, 5, 2); ld(B, 1, 6, 3); ld(C, 2, 7, 4); ld(D, 3, 8, 5); ld(E5, 4, 9, 6);

    float S[8];
#pragma unroll
    for (int i = 0; i < 8; ++i) S[i] = 0.f;
    float d1 = 0.f, d2 = 0.f, d3 = 0.f, d4 = 0.f;
    float Ap = 0.f, Aq = 0.f, Bp = 0.f, Bq = 0.f, Cp = 0.f, Cq = 0.f;

    auto body = [&](int J, Stage& st) {
        float k8[8], e8[8], w8[8], q8[8];
        dec8(st.kek, k8); dec8(st.kee, e8);
        dec8(st.kqw, w8); dec8(st.kqq, q8);
        float vj = b2f((ushort)st.vv);
        float beta = st.s0.x, qk = st.s0.y;
        float a1 = st.s0.z, a2 = st.s0.w, a3 = st.s1.x, a4 = st.s1.y;
        float qb1 = st.s1.z, qb2 = st.s1.w, qb3 = st.s2.x, qb4 = st.s2.y;
        // refill (consumed again 5 bodies later: needs ke rec J+7, kq J+12, vs J+9)
        {
            int rke = J + 7;  if (rke > NREC - 1) rke = NREC - 1;
            int rkq = J + 12; if (rkq > NREC - 1) rkq = NREC - 1;
            int rvs = J + 9;  if (rvs > NREC - 1) rvs = NREC - 1;
            ld(st, rke, rkq, rvs);
        }
        // compiler memory barrier: loads above cannot sink below this point
        asm volatile("" ::: "memory");
        // S update: t = J-2  (S becomes S_{J-2})
#pragma unroll
        for (int i = 0; i < 8; ++i) S[i] = fmaf(k8[i], d2, e8[i] * S[i]);
        // dots for t = J+3  (kw_{J+3} . S_{J-2})
        float pk = 0.f, pq = 0.f;
#pragma unroll
        for (int i = 0; i < 8; ++i) { pk = fmaf(w8[i], S[i], pk); pq = fmaf(q8[i], S[i], pq); }
        // scalar chain: t = J
        float pks = Cp + a1 * d1 + a2 * d2 + a3 * d3 + a4 * d4;
        float dl = beta * (vj - pks);
        float oo = Cq + qb1 * d1 + qb2 * d2 + qb3 * d3 + qb4 * d4 + qk * dl;
        if (J >= 0 && J < TB && l16 == 0) op[(size_t)J * 2048] = f2b(oo);
        // reduction pipeline rotate (4 shfl levels spread over 3 bodies)
        float tp = Bp + __shfl_xor(Bp, 4); Cp = tp + __shfl_xor(tp, 8);
        float tq = Bq + __shfl_xor(Bq, 4); Cq = tq + __shfl_xor(tq, 8);
        Bp = Ap + __shfl_xor(Ap, 2); Bq = Aq + __shfl_xor(Aq, 2);
        Ap = pk + __shfl_xor(pk, 1); Aq = pq + __shfl_xor(pq, 1);
        d4 = d3; d3 = d2; d2 = d1; d1 = dl;
    };

    int J = -2;
    for (int it = 0; it < 820; ++it) {   // 820*5 = 4100 bodies: J = -2 .. 4097
        body(J, A);
        body(J + 1, B);
        body(J + 2, C);
        body(J + 3, D);
        body(J + 4, E5);
        J += 5;
    }
}

// ---------------------------------------------------------------------------
// gated RMS norm: og = bf16( o*rsqrt(mean o^2+1e-5)*norm_w*sigmoid(gate+bg2) )
// ---------------------------------------------------------------------------
__global__ __launch_bounds__(256) void normgate_kernel(
    const ushort* __restrict__ o, const ushort* __restrict__ gate,
    const float* __restrict__ bg2, const float* __restrict__ norm_w,
    ushort* __restrict__ og) {
    const int lane = threadIdx.x & 63;
    const int wstart = (blockIdx.x * 256 + threadIdx.x) >> 6;
    const int nw = (gridDim.x * 256) >> 6;
    for (int pair = wstart; pair < TB * 16; pair += nw) {
        const int t = pair >> 4, h = pair & 15;
        const size_t basep = (size_t)t * 2048 + h * 128 + lane * 2;
        unsigned int ovu = *(const unsigned int*)(o + basep);
        float o0 = __uint_as_float(ovu << 16);
        float o1 = __uint_as_float(ovu & 0xffff0000u);
        float ss = o0 * o0 + o1 * o1;
#pragma unroll
        for (int m = 32; m >= 1; m >>= 1) ss += __shfl_xor(ss, m);
        float rn = rsqrtf(ss * (1.0f / 128.0f) + 1e-5f);
        const int dg = h * 128 + lane * 2;
        unsigned int gv = *(const unsigned int*)(gate + basep);
        float g0 = __uint_as_float(gv << 16) + bg2[dg];
        float g1 = __uint_as_float(gv & 0xffff0000u) + bg2[dg + 1];
        float w0 = norm_w[lane * 2], w1 = norm_w[lane * 2 + 1];
        float r0 = o0 * rn * w0 / (1.0f + expf(-g0));
        float r1 = o1 * rn * w1 / (1.0f + expf(-g1));
        unsigned int outw = (unsigned int)f2b(r0) | ((unsigned int)f2b(r1) << 16);
        *(unsigned int*)(og + basep) = outw;
    }
}

// ---------------------------------------------------------------------------
extern "C" void kernel_launch(void* const* d_in, const int* in_sizes, int n_in,
                              void* d_out, int out_size, void* d_ws, size_t ws_size,
                              hipStream_t stream) {
    const float* x = (const float*)d_in[0];
    const float* Wq = (const float*)d_in[1];
    const float* Wk = (const float*)d_in[2];
    const float* Wv = (const float*)d_in[3];
    const float* convq = (const float*)d_in[4];
    const float* convk = (const float*)d_in[5];
    const float* convv = (const float*)d_in[6];
    const float* A_log = (const float*)d_in[7];
    const float* dt_bias = (const float*)d_in[8];
    const float* Wsv = (const float*)d_in[9];
    const float* Wb1 = (const float*)d_in[10];
    const float* bb1 = (const float*)d_in[11];
    const float* Wb2 = (const float*)d_in[12];
    const float* bb2 = (const float*)d_in[13];
    const float* Wa1 = (const float*)d_in[14];
    const float* ba1 = (const float*)d_in[15];
    const float* Wa2 = (const float*)d_in[16];
    const float* ba2 = (const float*)d_in[17];
    const float* Wg1 = (const float*)d_in[18];
    const float* Wg2 = (const float*)d_in[19];
    const float* bg2 = (const float*)d_in[20];
    const float* norm_w = (const float*)d_in[21];
    const float* Wo = (const float*)d_in[22];

    // ---- workspace layout (bytes) ----
    const size_t PBATCH   = (size_t)16 * BHSH * 2;      // 87,116,800 per batch
    const size_t OFF_WQKV = 0;                          // 25,165,824
    const size_t OFF_XB   = OFF_WQKV + 25165824;        // 16,777,216
    const size_t OFF_WG1  = OFF_XB + 16777216;          //    524,288
    const size_t OFF_WG2  = OFF_WG1 + 524288;           //    524,288
    const size_t OFF_QKV  = OFF_WG2 + 524288;           // 50,331,648
    const size_t OFF_P    = OFF_QKV + 50331648;         // = 93,323,264
    const size_t NEED_B   = OFF_P + PBATCH;             // 180,440,064
    const size_t NEED_A   = OFF_P + 2 * PBATCH;         // 267,556,864
    if (ws_size < NEED_B) return;  // diagnostic guard
    const bool planA = (ws_size >= NEED_A);

    char* ws = (char*)d_ws;
    ushort* wqkv = (ushort*)(ws + OFF_WQKV);
    ushort* xb   = (ushort*)(ws + OFF_XB);
    ushort* wg1b = (ushort*)(ws + OFF_WG1);
    ushort* wg2b = (ushort*)(ws + OFF_WG2);
    ushort* qkvb = (ushort*)(ws + OFF_QKV);
    ushort* P    = (ushort*)(ws + OFF_P);
    // phase-3 aliases in the dead qkv region:
    ushort* gateb = qkvb;                               // +0        16,777,216
    ushort* xg1b  = (ushort*)(ws + OFF_QKV + 16777216); // +16.78M    1,048,576
    ushort* ogb   = (ushort*)(ws + OFF_QKV + 17825792); // +17.83M   16,777,216
    ushort* wob   = (ushort*)(ws + OFF_QKV + 34603008); // +34.60M    8,388,608
    // scan output: planB -> xb region (per batch, 16.7MB);
    //              planA -> wqkv+xb contiguous span (both batches, 33.5MB; both dead)
    ushort* obp = planA ? (ushort*)(ws + OFF_WQKV) : xb;

    // weight casts
    cast_f32_bf16<<<512, 256, 0, stream>>>(Wq, wqkv, 4194304);
    cast_f32_bf16<<<512, 256, 0, stream>>>(Wk, wqkv + 4194304, 4194304);
    cast_f32_bf16<<<512, 256, 0, stream>>>(Wv, wqkv + 8388608, 4194304);
    cast_f32_bf16<<<64, 256, 0, stream>>>(Wg1, wg1b, 262144);
    cast_f32_bf16<<<64, 256, 0, stream>>>(Wg2, wg2b, 262144);

    if (planA) {
        // phase 1: produce P + gate for both batches (gate written per batch into
        // the qkv region AFTER conv consumes qkv -> need gate kept per batch:
        // store gate for batch b at gateb + b*TB*2048? gate region is 16.7MB =
        // one batch. Run gate GEMMs in phase 3 instead (xb is dead then; re-cast x).
        for (int b = 0; b < 2; ++b) {
            cast_f32_bf16<<<512, 256, 0, stream>>>(x + (size_t)b * TB * 2048, xb, TB * 2048);
            gemm_bf16<ushort><<<dim3(48, TB / 128), 256, 0, stream>>>(xb, wqkv, qkvb, TB, 6144, 2048);
            conv_stats_kernel<<<TB * 16 / 8, 256, 0, stream>>>(qkvb, convq, convk, convv, Wsv,
                Wb1, bb1, Wb2, bb2, Wa1, ba1, Wa2, ba2, A_log, dt_bias,
                P + (size_t)b * 16 * BHSH);
        }
        prepass_kernel<<<32 * 1024, 256, 0, stream>>>(P);
        // ONE scan over both batches (256 blocks) -> obp (wqkv+xb span, now dead)
        scan_kernel<<<256, 256, 0, stream>>>(P, obp);
        // phase 3 (wqkv destroyed; qkv region reused for gate/xg1/og/wob)
        cast_f32_bf16<<<512, 256, 0, stream>>>(Wo, wob, 4194304);
        for (int b = 0; b < 2; ++b) {
            // xb overlaps obp tail in planA -> stage x cast into gateb temporarily?
            // No: gate pipeline needs its own x. Use xg1b region? too small.
            // Use ogb region (16.7MB) as x staging, then write og into gateb after
            // gate GEMM output is consumed... simpler: stage x into ogb, gate into
            // gateb, og into ogb (overwrites x staging after it is consumed).
            ushort* xstage = ogb;  // 16.7MB
            cast_f32_bf16<<<512, 256, 0, stream>>>(x + (size_t)b * TB * 2048, xstage, TB * 2048);
            gemm_bf16<ushort><<<dim3(1, TB / 128), 256, 0, stream>>>(xstage, wg1b, xg1b, TB, 128, 2048);
            gemm_bf16<ushort><<<dim3(16, TB / 128), 256, 0, stream>>>(xg1b, wg2b, gateb, TB, 2048, 128);
            // og overwrites xstage (x no longer needed this batch)
            normgate_kernel<<<2048, 256, 0, stream>>>(obp + (size_t)b * TB * 2048, gateb, bg2, norm_w, ogb);
            gemm_bf16<float><<<dim3(16, TB / 128), 256, 0, stream>>>(ogb, wob,
                (float*)d_out + (size_t)b * TB * 2048, TB, 2048, 2048);
        }
    } else {
        for (int b = 0; b < 2; ++b) {
            const float* xbp = x + (size_t)b * TB * 2048;
            float* outp = (float*)d_out + (size_t)b * TB * 2048;
            cast_f32_bf16<<<512, 256, 0, stream>>>(xbp, xb, TB * 2048);
            gemm_bf16<ushort><<<dim3(48, TB / 128), 256, 0, stream>>>(xb, wqkv, qkvb, TB, 6144, 2048);
            conv_stats_kernel<<<TB * 16 / 8, 256, 0, stream>>>(qkvb, convq, convk, convv, Wsv,
                Wb1, bb1, Wb2, bb2, Wa1, ba1, Wa2, ba2, A_log, dt_bias, P);
            gemm_bf16<ushort><<<dim3(1, TB / 128), 256, 0, stream>>>(xb, wg1b, xg1b, TB, 128, 2048);
            gemm_bf16<ushort><<<dim3(16, TB / 128), 256, 0, stream>>>(xg1b, wg2b, gateb, TB, 2048, 128);
            cast_f32_bf16<<<512, 256, 0, stream>>>(Wo, wob, 4194304);
            prepass_kernel<<<16 * 1024, 256, 0, stream>>>(P);
            scan_kernel<<<128, 256, 0, stream>>>(P, xb);   // xb dead -> ob
            normgate_kernel<<<2048, 256, 0, stream>>>(xb, gateb, bg2, norm_w, ogb);
            gemm_bf16<float><<<dim3(16, TB / 128), 256, 0, stream>>>(ogb, wob, outp, TB, 2048, 2048);
        }
    }
}

// Round 7
// 2445.531 us; speedup vs baseline: 2.5098x; 1.1205x over previous
//
#include <hip/hip_runtime.h>
#include <hip/hip_bf16.h>

// ---------------------------------------------------------------------------
// SurpriseKimiDeltaAttention  (B=2, T=4096, H=2048, NH=16, DK=DV=128, CONV=4)
// Pipeline: cast -> qkv GEMM -> conv/stats -> gate GEMMs -> prepass ->
//           scan (reg-pipelined, D=5 deferral, 5-stage prefetch) ->
//           normgate -> out GEMM
// Record (per h,t; 664 shorts = 1328 B), index r = t+4 (recs 0..3 zero pads):
//   bytes: kw@0 qw@256 k@512 E@768 v@1024 sc@1280 (f32[12]: beta,qk,a1..4,qb1..4)
// Scan recurrence (deferral D=5):
//   pk_t = kw_t . S_{t-5} + sum_m a_m(t) d_{t-m};  d_t = beta (v_t - pk_t)
//   o_t  = qw_t . S_{t-5} + sum_m qb_m d_{t-m} + qk d_t
//   S_t  = E_t * S_{t-1} + k_t d_t
// Plan A (ws >= ~267.6MB): both batches' P resident -> ONE scan launch (256 blk).
// Plan B (ws >= ~180.4MB): per-batch sequential.
// ---------------------------------------------------------------------------

typedef __attribute__((ext_vector_type(8))) short bf16x8;
typedef __attribute__((ext_vector_type(4))) float floatx4;

#define TB 4096
#define RSH 664                      // shorts per record
#define RB 1328                      // bytes per record
#define NREC 4100                    // 4 zero pads + TB
#define BHSH ((size_t)NREC * RSH)    // shorts per (b,h) stream
#define TAILPAD (16 * RB)            // benign-overread pad after last stream

__device__ __forceinline__ float b2f(ushort u) {
    union { unsigned int u; float f; } c; c.u = ((unsigned int)u) << 16; return c.f;
}
__device__ __forceinline__ ushort f2b(float f) {
    union { float f; unsigned int u; } c; c.f = f;
    unsigned int r = (c.u + 0x7fffu + ((c.u >> 16) & 1u)) >> 16;
    return (ushort)r;
}
__device__ __forceinline__ float silu(float x) { return x / (1.0f + expf(-x)); }

// ---------------------------------------------------------------------------
__global__ __launch_bounds__(256) void cast_f32_bf16(const float* __restrict__ in,
                                                     ushort* __restrict__ out, int n) {
    int i = (blockIdx.x * 256 + threadIdx.x) * 4;
    int stride = gridDim.x * 256 * 4;
    for (; i + 3 < n; i += stride) {
        float4 v = *(const float4*)(in + i);
        ushort4 u;
        u.x = f2b(v.x); u.y = f2b(v.y); u.z = f2b(v.z); u.w = f2b(v.w);
        *(ushort4*)(out + i) = u;
    }
}

// ---------------------------------------------------------------------------
// bf16 MFMA GEMM: C[M][N] = A[M][K] @ B[N][K]^T  (row-major, K contiguous)
// ---------------------------------------------------------------------------
template <typename CT>
__global__ __launch_bounds__(256) void gemm_bf16(const ushort* __restrict__ A,
                                                 const ushort* __restrict__ B,
                                                 CT* __restrict__ C, int M, int N, int K) {
    __shared__ ushort As[128 * 40];
    __shared__ ushort Bs[128 * 40];
    const int tid = threadIdx.x;
    const int lane = tid & 63, wid = tid >> 6;
    const int wr = wid >> 1, wc = wid & 1;
    const int bm = blockIdx.y, bn = blockIdx.x;

    const int r0 = tid >> 2;
    const int kc0 = (tid & 3) * 8;
    const size_t aoff0 = (size_t)(bm * 128 + r0) * K + kc0;
    const size_t aoff1 = aoff0 + (size_t)64 * K;
    const size_t boff0 = (size_t)(bn * 128 + r0) * K + kc0;
    const size_t boff1 = boff0 + (size_t)64 * K;
    const int lw0 = r0 * 40 + kc0;
    const int lw1 = (r0 + 64) * 40 + kc0;

    const int arow = wr * 64 + (lane & 15);
    const int brow = wc * 64 + (lane & 15);
    const int kg = (lane >> 4) * 8;

    floatx4 acc[4][4];
#pragma unroll
    for (int m = 0; m < 4; ++m)
#pragma unroll
        for (int n = 0; n < 4; ++n) acc[m][n] = (floatx4){0.f, 0.f, 0.f, 0.f};

    uint4 ra0 = *(const uint4*)(A + aoff0);
    uint4 ra1 = *(const uint4*)(A + aoff1);
    uint4 rb0 = *(const uint4*)(B + boff0);
    uint4 rb1 = *(const uint4*)(B + boff1);

    for (int kt = 32; kt <= K; kt += 32) {
        __syncthreads();
        *(uint4*)(As + lw0) = ra0;
        *(uint4*)(As + lw1) = ra1;
        *(uint4*)(Bs + lw0) = rb0;
        *(uint4*)(Bs + lw1) = rb1;
        __syncthreads();
        if (kt < K) {
            ra0 = *(const uint4*)(A + aoff0 + kt);
            ra1 = *(const uint4*)(A + aoff1 + kt);
            rb0 = *(const uint4*)(B + boff0 + kt);
            rb1 = *(const uint4*)(B + boff1 + kt);
        }
        bf16x8 af[4], bfr[4];
#pragma unroll
        for (int m = 0; m < 4; ++m) af[m] = *(const bf16x8*)(As + (arow + m * 16) * 40 + kg);
#pragma unroll
        for (int n = 0; n < 4; ++n) bfr[n] = *(const bf16x8*)(Bs + (brow + n * 16) * 40 + kg);
#pragma unroll
        for (int m = 0; m < 4; ++m)
#pragma unroll
            for (int n = 0; n < 4; ++n)
                acc[m][n] = __builtin_amdgcn_mfma_f32_16x16x32_bf16(af[m], bfr[n], acc[m][n], 0, 0, 0);
    }

    const int crow0 = bm * 128 + wr * 64 + (lane >> 4) * 4;
    const int ccol0 = bn * 128 + wc * 64 + (lane & 15);
#pragma unroll
    for (int m = 0; m < 4; ++m)
#pragma unroll
        for (int n = 0; n < 4; ++n)
#pragma unroll
            for (int j = 0; j < 4; ++j) {
                int row = crow0 + m * 16 + j;
                int col = ccol0 + n * 16;
                if constexpr (sizeof(CT) == 2)
                    C[(size_t)row * N + col] = (CT)f2b(acc[m][n][j]);
                else
                    C[(size_t)row * N + col] = (CT)acc[m][n][j];
            }
}

// ---------------------------------------------------------------------------
// conv + silu + surprise stats + beta/amp MLPs -> record fields (one batch)
// ---------------------------------------------------------------------------
__global__ __launch_bounds__(256) void conv_stats_kernel(
    const ushort* __restrict__ qkv,
    const float* __restrict__ convq, const float* __restrict__ convk,
    const float* __restrict__ convv, const float* __restrict__ Wsv,
    const float* __restrict__ Wb1, const float* __restrict__ bb1,
    const float* __restrict__ Wb2, const float* __restrict__ bb2,
    const float* __restrict__ Wa1, const float* __restrict__ ba1,
    const float* __restrict__ Wa2, const float* __restrict__ ba2,
    const float* __restrict__ A_log, const float* __restrict__ dt_bias,
    ushort* __restrict__ P) {
    __shared__ ushort wsv_s[128 * 136];
    __shared__ float k_sh[4][128];
    // zero-fill pad records 0..3 for each h
    if (blockIdx.x == 0) {
        for (int z = threadIdx.x; z < 16 * 4 * RSH; z += 256) {
            int hh = z / (4 * RSH);
            int off = z % (4 * RSH);
            P[(size_t)hh * BHSH + off] = 0;
        }
    }
    for (int i = threadIdx.x; i < 128 * 128; i += 256) {
        int row = i >> 7, col = i & 127;
        wsv_s[row * 136 + col] = f2b(Wsv[i]);
    }
    __syncthreads();
    const int wid = threadIdx.x >> 6, lane = threadIdx.x & 63;

    for (int it = 0; it < 2; ++it) {
        const int pair = blockIdx.x * 8 + it * 4 + wid;   // [0, TB*16)
        const int t = pair >> 4, h = pair & 15;
        const int c0 = h * 128 + lane, c1 = c0 + 64;

        float wq[4], wq2[4], wk[4], wk2[4], wv[4], wv2[4];
#pragma unroll
        for (int i2 = 0; i2 < 4; ++i2) {
            wq[i2] = convq[c0 * 4 + i2]; wq2[i2] = convq[c1 * 4 + i2];
            wk[i2] = convk[c0 * 4 + i2]; wk2[i2] = convk[c1 * 4 + i2];
            wv[i2] = convv[c0 * 4 + i2]; wv2[i2] = convv[c1 * 4 + i2];
        }
        float aq0 = 0, aq1 = 0, ak0 = 0, ak1 = 0, av0 = 0, av1 = 0;
#pragma unroll
        for (int i2 = 0; i2 < 4; ++i2) {
            int tt = t - 3 + i2;
            if (tt >= 0) {
                const ushort* rowp = qkv + (size_t)tt * 6144 + h * 128;
                aq0 = fmaf(b2f(rowp[lane]), wq[i2], aq0);
                aq1 = fmaf(b2f(rowp[lane + 64]), wq2[i2], aq1);
                ak0 = fmaf(b2f(rowp[2048 + lane]), wk[i2], ak0);
                ak1 = fmaf(b2f(rowp[2048 + lane + 64]), wk2[i2], ak1);
                av0 = fmaf(b2f(rowp[4096 + lane]), wv[i2], av0);
                av1 = fmaf(b2f(rowp[4096 + lane + 64]), wv2[i2], av1);
            }
        }
        float q0 = silu(aq0), q1 = silu(aq1);
        float k0 = silu(ak0), k1 = silu(ak1);
        float v0 = silu(av0), v1 = silu(av1);

        __syncthreads();
        k_sh[wid][lane] = k0;
        k_sh[wid][lane + 64] = k1;
        __syncthreads();

        float vh0 = 0.f, vh1 = 0.f;
        const ushort* wr0 = wsv_s + lane * 136;
        const ushort* wr1 = wsv_s + (lane + 64) * 136;
#pragma unroll 4
        for (int j = 0; j < 128; j += 8) {
            float4 ka = *(const float4*)&k_sh[wid][j];
            float4 kb = *(const float4*)&k_sh[wid][j + 4];
            uint4 wa = *(const uint4*)(wr0 + j);
            uint4 wb = *(const uint4*)(wr1 + j);
            vh0 = fmaf(__uint_as_float(wa.x << 16), ka.x, vh0);
            vh0 = fmaf(__uint_as_float(wa.x & 0xffff0000u), ka.y, vh0);
            vh0 = fmaf(__uint_as_float(wa.y << 16), ka.z, vh0);
            vh0 = fmaf(__uint_as_float(wa.y & 0xffff0000u), ka.w, vh0);
            vh0 = fmaf(__uint_as_float(wa.z << 16), kb.x, vh0);
            vh0 = fmaf(__uint_as_float(wa.z & 0xffff0000u), kb.y, vh0);
            vh0 = fmaf(__uint_as_float(wa.w << 16), kb.z, vh0);
            vh0 = fmaf(__uint_as_float(wa.w & 0xffff0000u), kb.w, vh0);
            vh1 = fmaf(__uint_as_float(wb.x << 16), ka.x, vh1);
            vh1 = fmaf(__uint_as_float(wb.x & 0xffff0000u), ka.y, vh1);
            vh1 = fmaf(__uint_as_float(wb.y << 16), ka.z, vh1);
            vh1 = fmaf(__uint_as_float(wb.y & 0xffff0000u), ka.w, vh1);
            vh1 = fmaf(__uint_as_float(wb.z << 16), kb.x, vh1);
            vh1 = fmaf(__uint_as_float(wb.z & 0xffff0000u), kb.y, vh1);
            vh1 = fmaf(__uint_as_float(wb.w << 16), kb.z, vh1);
            vh1 = fmaf(__uint_as_float(wb.w & 0xffff0000u), kb.w, vh1);
        }

        float e0 = vh0 - v0, e1 = vh1 - v1;
        float se2 = e0 * e0 + e1 * e1;
        float sl1 = fabsf(e0) + fabsf(e1);
        float shv = vh0 * v0 + vh1 * v1;
        float shh = vh0 * vh0 + vh1 * vh1;
        float svv = v0 * v0 + v1 * v1;
        float sk2 = k0 * k0 + k1 * k1;
        float sq2 = q0 * q0 + q1 * q1;
#pragma unroll
        for (int m = 32; m >= 1; m >>= 1) {
            se2 += __shfl_xor(se2, m);
            sl1 += __shfl_xor(sl1, m);
            shv += __shfl_xor(shv, m);
            shh += __shfl_xor(shh, m);
            svv += __shfl_xor(svv, m);
            sk2 += __shfl_xor(sk2, m);
            sq2 += __shfl_xor(sq2, m);
        }
        float s_l2 = sqrtf(se2 + 1e-6f);
        float s_l1 = sl1;
        float s_cos = 1.0f - shv / (sqrtf(shh + 1e-6f) * sqrtf(svv + 1e-6f) + 1e-6f);

        const int j2 = lane & 31;
        const float* W1 = (lane < 32) ? Wb1 : Wa1;
        const float* b1 = (lane < 32) ? bb1 : ba1;
        const float* W2 = (lane < 32) ? Wb2 : Wa2;
        float pre = W1[j2 * 3] * s_l2 + W1[j2 * 3 + 1] * s_l1 + W1[j2 * 3 + 2] * s_cos + b1[j2];
        float val = W2[j2] * silu(pre);
#pragma unroll
        for (int m = 16; m >= 1; m >>= 1) val += __shfl_xor(val, m);
        float pre_b = __shfl(val, 0) + bb2[0];
        float pre_a = __shfl(val, 32) + ba2[0];
        float betav = 1.0f / (1.0f + expf(-pre_b));
        float amp = pre_a;

        float knorm = sqrtf(sk2);
        float rinv = amp / fmaxf(knorm, 1e-12f);
        float ah = expf(A_log[h]);
        float gr0 = fmaf(k0, rinv, dt_bias[c0]);
        float gr1 = fmaf(k1, rinv, dt_bias[c1]);
        float sp0 = (gr0 > 20.f) ? gr0 : log1pf(expf(gr0));
        float sp1 = (gr1 > 20.f) ? gr1 : log1pf(expf(gr1));

        ushort* rec = P + (size_t)h * BHSH + (size_t)(t + 4) * RSH;
        float kinv = rsqrtf(sk2 + 1e-6f);
        float qinv = rsqrtf(sq2 + 1e-6f) * 0.08838834764831845f;  // * DK^-0.5
        rec[128 + lane]      = f2b(q0 * qinv);     // q~ (prepass overwrites with qw)
        rec[128 + lane + 64] = f2b(q1 * qinv);
        rec[256 + lane]      = f2b(k0 * kinv);     // raw normalized k
        rec[256 + lane + 64] = f2b(k1 * kinv);
        rec[384 + lane]      = f2b(expf(-ah * sp0));  // E = exp(g)
        rec[384 + lane + 64] = f2b(expf(-ah * sp1));
        rec[512 + lane]      = f2b(v0);
        rec[512 + lane + 64] = f2b(v1);
        if (lane == 0) *(float*)(rec + 640) = betav;
    }
}

// ---------------------------------------------------------------------------
// prepass: kw = k*W5, qw = q~*W5 (W5 = prod_{i=0..4} E_{t-i}), scalars
// qk, a1..a4, qb1..qb4.  One wave per record; in-place.
// ---------------------------------------------------------------------------
__global__ __launch_bounds__(256) void prepass_kernel(ushort* __restrict__ P) {
    const int g = blockIdx.x * 4 + (threadIdx.x >> 6);
    const int bh = g >> 12, t = g & 4095;
    const int lane = threadIdx.x & 63;
    ushort* rec = P + (size_t)bh * BHSH + (size_t)(t + 4) * RSH;

    float kt0 = b2f(rec[256 + lane]), kt1 = b2f(rec[256 + lane + 64]);
    float qt0 = b2f(rec[128 + lane]), qt1 = b2f(rec[128 + lane + 64]);
    float a[4], qb[4];
    float wa = b2f(rec[384 + lane]), wb = b2f(rec[384 + lane + 64]);  // E_t
    float qk = qt0 * kt0 + qt1 * kt1;
#pragma unroll
    for (int m = 1; m <= 4; ++m) {
        const ushort* rp = rec - (size_t)m * RSH;
        float kp0 = b2f(rp[256 + lane]), kp1 = b2f(rp[256 + lane + 64]);
        a[m - 1]  = kt0 * wa * kp0 + kt1 * wb * kp1;
        qb[m - 1] = qt0 * wa * kp0 + qt1 * wb * kp1;
        float ep0 = b2f(rp[384 + lane]), ep1 = b2f(rp[384 + lane + 64]);
        wa *= ep0; wb *= ep1;   // after loop: wa = W5 per dim
    }
#pragma unroll
    for (int m = 32; m >= 1; m >>= 1) {
        qk += __shfl_xor(qk, m);
        a[0] += __shfl_xor(a[0], m); a[1] += __shfl_xor(a[1], m);
        a[2] += __shfl_xor(a[2], m); a[3] += __shfl_xor(a[3], m);
        qb[0] += __shfl_xor(qb[0], m); qb[1] += __shfl_xor(qb[1], m);
        qb[2] += __shfl_xor(qb[2], m); qb[3] += __shfl_xor(qb[3], m);
    }
    rec[lane]            = f2b(kt0 * wa);
    rec[lane + 64]       = f2b(kt1 * wb);
    rec[128 + lane]      = f2b(qt0 * wa);
    rec[128 + lane + 64] = f2b(qt1 * wb);
    if (lane == 0) {
        float* sc = (float*)(rec + 640);
        sc[1] = qk;
        sc[2] = a[0]; sc[3] = a[1]; sc[4] = a[2]; sc[5] = a[3];
        sc[6] = qb[0]; sc[7] = qb[1]; sc[8] = qb[2]; sc[9] = qb[3];
    }
}

// ---------------------------------------------------------------------------
// scan: register-pipelined, 5-stage prefetch (distance 5).
// __launch_bounds__(256,1): 1 wave/SIMD -> up to 512 VGPR, no spill.
// Rolling load pointers (+RB per body); tail-padded P makes clamps unneeded.
// XCD swizzle: s = bid & smask (stream), c = bid >> sshift (col-block) so all
// 8 col-blocks of a stream share bid%8 -> same XCD L2.
// ---------------------------------------------------------------------------
struct Stage {
    uint4 kek, kee, kqw, kqq;
    uint vv;
    float4 s0, s1;
    float2 s2;
};

__device__ __forceinline__ void dec8(uint4 u, float* f) {
    f[0] = __uint_as_float(u.x << 16); f[1] = __uint_as_float(u.x & 0xffff0000u);
    f[2] = __uint_as_float(u.y << 16); f[3] = __uint_as_float(u.y & 0xffff0000u);
    f[4] = __uint_as_float(u.z << 16); f[5] = __uint_as_float(u.z & 0xffff0000u);
    f[6] = __uint_as_float(u.w << 16); f[7] = __uint_as_float(u.w & 0xffff0000u);
}

__global__ __launch_bounds__(256, 1) void scan_kernel(const ushort* __restrict__ P,
                                                      ushort* __restrict__ ob,
                                                      int smask, int sshift) {
    const int tid = threadIdx.x;
    const int l16 = tid & 15, cg = tid >> 4;
    const int s = blockIdx.x & smask;
    const int c = blockIdx.x >> sshift;
    const int b = s >> 4;
    const int h = s & 15;
    const int col = c * 16 + cg;
    const char* gb = (const char*)(P + (size_t)s * BHSH);
    ushort* op = ob + (size_t)b * TB * 2048 + h * 128 + col;
    const int lo = l16 * 16;
    const int co = col * 2;

    auto ldinit = [&](Stage& st, int rke, int rkq, int rvs) {
        const char* pa = gb + (size_t)rke * RB;
        const char* pb = gb + (size_t)rkq * RB;
        const char* pc = gb + (size_t)rvs * RB;
        st.kek = *(const uint4*)(pa + 512 + lo);
        st.kee = *(const uint4*)(pa + 768 + lo);
        st.kqw = *(const uint4*)(pb + 0 + lo);
        st.kqq = *(const uint4*)(pb + 256 + lo);
        st.vv  = *(const ushort*)(pc + 1024 + co);
        st.s0  = *(const float4*)(pc + 1280);
        st.s1  = *(const float4*)(pc + 1296);
        st.s2  = *(const float2*)(pc + 1312);
    };

    Stage A, B, C, D, E5;
    ldinit(A, 0, 5, 2); ldinit(B, 1, 6, 3); ldinit(C, 2, 7, 4);
    ldinit(D, 3, 8, 5); ldinit(E5, 4, 9, 6);

    // rolling refill pointers: body J refills ke rec J+7, kq rec J+12, vs rec J+9
    const char* pke = gb + (size_t)5 * RB;    // first body J=-2
    const char* pkq = gb + (size_t)10 * RB;
    const char* pvs = gb + (size_t)7 * RB;

    float S[8];
#pragma unroll
    for (int i = 0; i < 8; ++i) S[i] = 0.f;
    float d1 = 0.f, d2 = 0.f, d3 = 0.f, d4 = 0.f;
    float Ap = 0.f, Aq = 0.f, Bp = 0.f, Bq = 0.f, Cp = 0.f, Cq = 0.f;

    auto body = [&](int J, Stage& st) {
        float k8[8], e8[8], w8[8], q8[8];
        dec8(st.kek, k8); dec8(st.kee, e8);
        dec8(st.kqw, w8); dec8(st.kqq, q8);
        float vj = b2f((ushort)st.vv);
        float beta = st.s0.x, qk = st.s0.y;
        float a1 = st.s0.z, a2 = st.s0.w, a3 = st.s1.x, a4 = st.s1.y;
        float qb1 = st.s1.z, qb2 = st.s1.w, qb3 = st.s2.x, qb4 = st.s2.y;
        // refill (consumed 5 bodies later); rolling pointers, no muls/clamps
        st.kek = *(const uint4*)(pke + 512 + lo);
        st.kee = *(const uint4*)(pke + 768 + lo);
        st.kqw = *(const uint4*)(pkq + 0 + lo);
        st.kqq = *(const uint4*)(pkq + 256 + lo);
        st.vv  = *(const ushort*)(pvs + 1024 + co);
        st.s0  = *(const float4*)(pvs + 1280);
        st.s1  = *(const float4*)(pvs + 1296);
        st.s2  = *(const float2*)(pvs + 1312);
        pke += RB; pkq += RB; pvs += RB;
        // compiler memory barrier: refill loads cannot sink below
        asm volatile("" ::: "memory");
        // S update: t = J-2
#pragma unroll
        for (int i = 0; i < 8; ++i) S[i] = fmaf(k8[i], d2, e8[i] * S[i]);
        // dots for t = J+3  (kw_{J+3} . S_{J-2})
        float pk = 0.f, pq = 0.f;
#pragma unroll
        for (int i = 0; i < 8; ++i) { pk = fmaf(w8[i], S[i], pk); pq = fmaf(q8[i], S[i], pq); }
        // scalar chain: t = J
        float pks = Cp + a1 * d1 + a2 * d2 + a3 * d3 + a4 * d4;
        float dl = beta * (vj - pks);
        float oo = Cq + qb1 * d1 + qb2 * d2 + qb3 * d3 + qb4 * d4 + qk * dl;
        if (J >= 0 && J < TB && l16 == 0) op[(size_t)J * 2048] = f2b(oo);
        // reduction pipeline rotate (4 shfl levels spread over 3 bodies)
        float tp = Bp + __shfl_xor(Bp, 4); Cp = tp + __shfl_xor(tp, 8);
        float tq = Bq + __shfl_xor(Bq, 4); Cq = tq + __shfl_xor(tq, 8);
        Bp = Ap + __shfl_xor(Ap, 2); Bq = Aq + __shfl_xor(Aq, 2);
        Ap = pk + __shfl_xor(pk, 1); Aq = pq + __shfl_xor(pq, 1);
        d4 = d3; d3 = d2; d2 = d1; d1 = dl;
    };

    int J = -2;
    for (int it = 0; it < 820; ++it) {   // 820*5 = 4100 bodies: J = -2 .. 4097
        body(J, A);
        body(J + 1, B);
        body(J + 2, C);
        body(J + 3, D);
        body(J + 4, E5);
        J += 5;
    }
}

// ---------------------------------------------------------------------------
// gated RMS norm: og = bf16( o*rsqrt(mean o^2+1e-5)*norm_w*sigmoid(gate+bg2) )
// ---------------------------------------------------------------------------
__global__ __launch_bounds__(256) void normgate_kernel(
    const ushort* __restrict__ o, const ushort* __restrict__ gate,
    const float* __restrict__ bg2, const float* __restrict__ norm_w,
    ushort* __restrict__ og) {
    const int lane = threadIdx.x & 63;
    const int wstart = (blockIdx.x * 256 + threadIdx.x) >> 6;
    const int nw = (gridDim.x * 256) >> 6;
    for (int pair = wstart; pair < TB * 16; pair += nw) {
        const int t = pair >> 4, h = pair & 15;
        const size_t basep = (size_t)t * 2048 + h * 128 + lane * 2;
        unsigned int ovu = *(const unsigned int*)(o + basep);
        float o0 = __uint_as_float(ovu << 16);
        float o1 = __uint_as_float(ovu & 0xffff0000u);
        float ss = o0 * o0 + o1 * o1;
#pragma unroll
        for (int m = 32; m >= 1; m >>= 1) ss += __shfl_xor(ss, m);
        float rn = rsqrtf(ss * (1.0f / 128.0f) + 1e-5f);
        const int dg = h * 128 + lane * 2;
        unsigned int gv = *(const unsigned int*)(gate + basep);
        float g0 = __uint_as_float(gv << 16) + bg2[dg];
        float g1 = __uint_as_float(gv & 0xffff0000u) + bg2[dg + 1];
        float w0 = norm_w[lane * 2], w1 = norm_w[lane * 2 + 1];
        float r0 = o0 * rn * w0 / (1.0f + expf(-g0));
        float r1 = o1 * rn * w1 / (1.0f + expf(-g1));
        unsigned int outw = (unsigned int)f2b(r0) | ((unsigned int)f2b(r1) << 16);
        *(unsigned int*)(og + basep) = outw;
    }
}

// ---------------------------------------------------------------------------
extern "C" void kernel_launch(void* const* d_in, const int* in_sizes, int n_in,
                              void* d_out, int out_size, void* d_ws, size_t ws_size,
                              hipStream_t stream) {
    const float* x = (const float*)d_in[0];
    const float* Wq = (const float*)d_in[1];
    const float* Wk = (const float*)d_in[2];
    const float* Wv = (const float*)d_in[3];
    const float* convq = (const float*)d_in[4];
    const float* convk = (const float*)d_in[5];
    const float* convv = (const float*)d_in[6];
    const float* A_log = (const float*)d_in[7];
    const float* dt_bias = (const float*)d_in[8];
    const float* Wsv = (const float*)d_in[9];
    const float* Wb1 = (const float*)d_in[10];
    const float* bb1 = (const float*)d_in[11];
    const float* Wb2 = (const float*)d_in[12];
    const float* bb2 = (const float*)d_in[13];
    const float* Wa1 = (const float*)d_in[14];
    const float* ba1 = (const float*)d_in[15];
    const float* Wa2 = (const float*)d_in[16];
    const float* ba2 = (const float*)d_in[17];
    const float* Wg1 = (const float*)d_in[18];
    const float* Wg2 = (const float*)d_in[19];
    const float* bg2 = (const float*)d_in[20];
    const float* norm_w = (const float*)d_in[21];
    const float* Wo = (const float*)d_in[22];

    // ---- workspace layout (bytes) ----
    const size_t PBATCH   = (size_t)16 * BHSH * 2;      // 87,116,800 per batch
    const size_t OFF_WQKV = 0;                          // 25,165,824
    const size_t OFF_XB   = OFF_WQKV + 25165824;        // 16,777,216
    const size_t OFF_WG1  = OFF_XB + 16777216;          //    524,288
    const size_t OFF_WG2  = OFF_WG1 + 524288;           //    524,288
    const size_t OFF_QKV  = OFF_WG2 + 524288;           // 50,331,648
    const size_t OFF_P    = OFF_QKV + 50331648;         // = 93,323,264
    const size_t NEED_B   = OFF_P + PBATCH + TAILPAD;   // ~180.5 MB
    const size_t NEED_A   = OFF_P + 2 * PBATCH + TAILPAD;  // ~267.6 MB
    if (ws_size < NEED_B) return;  // diagnostic guard
    const bool planA = (ws_size >= NEED_A);

    char* ws = (char*)d_ws;
    ushort* wqkv = (ushort*)(ws + OFF_WQKV);
    ushort* xb   = (ushort*)(ws + OFF_XB);
    ushort* wg1b = (ushort*)(ws + OFF_WG1);
    ushort* wg2b = (ushort*)(ws + OFF_WG2);
    ushort* qkvb = (ushort*)(ws + OFF_QKV);
    ushort* P    = (ushort*)(ws + OFF_P);
    // phase-3 aliases in the dead qkv region:
    ushort* gateb = qkvb;                               // +0        16,777,216
    ushort* xg1b  = (ushort*)(ws + OFF_QKV + 16777216); // +16.78M    1,048,576
    ushort* ogb   = (ushort*)(ws + OFF_QKV + 17825792); // +17.83M   16,777,216
    ushort* wob   = (ushort*)(ws + OFF_QKV + 34603008); // +34.60M    8,388,608
    // scan output: planB -> xb region (per batch, 16.7MB);
    //              planA -> wqkv+xb contiguous span (both batches, 33.5MB; both dead)
    ushort* obp = planA ? (ushort*)(ws + OFF_WQKV) : xb;

    // weight casts
    cast_f32_bf16<<<512, 256, 0, stream>>>(Wq, wqkv, 4194304);
    cast_f32_bf16<<<512, 256, 0, stream>>>(Wk, wqkv + 4194304, 4194304);
    cast_f32_bf16<<<512, 256, 0, stream>>>(Wv, wqkv + 8388608, 4194304);
    cast_f32_bf16<<<64, 256, 0, stream>>>(Wg1, wg1b, 262144);
    cast_f32_bf16<<<64, 256, 0, stream>>>(Wg2, wg2b, 262144);

    if (planA) {
        for (int b = 0; b < 2; ++b) {
            cast_f32_bf16<<<512, 256, 0, stream>>>(x + (size_t)b * TB * 2048, xb, TB * 2048);
            gemm_bf16<ushort><<<dim3(48, TB / 128), 256, 0, stream>>>(xb, wqkv, qkvb, TB, 6144, 2048);
            conv_stats_kernel<<<TB * 16 / 8, 256, 0, stream>>>(qkvb, convq, convk, convv, Wsv,
                Wb1, bb1, Wb2, bb2, Wa1, ba1, Wa2, ba2, A_log, dt_bias,
                P + (size_t)b * 16 * BHSH);
        }
        prepass_kernel<<<32 * 1024, 256, 0, stream>>>(P);
        // ONE scan over both batches (256 blocks) -> obp (wqkv+xb span, now dead)
        scan_kernel<<<256, 256, 0, stream>>>(P, obp, 31, 5);
        // phase 3 (wqkv destroyed; qkv region reused for gate/xg1/og/wob)
        cast_f32_bf16<<<512, 256, 0, stream>>>(Wo, wob, 4194304);
        for (int b = 0; b < 2; ++b) {
            ushort* xstage = ogb;  // 16.7MB staging for x (og written later)
            cast_f32_bf16<<<512, 256, 0, stream>>>(x + (size_t)b * TB * 2048, xstage, TB * 2048);
            gemm_bf16<ushort><<<dim3(1, TB / 128), 256, 0, stream>>>(xstage, wg1b, xg1b, TB, 128, 2048);
            gemm_bf16<ushort><<<dim3(16, TB / 128), 256, 0, stream>>>(xg1b, wg2b, gateb, TB, 2048, 128);
            normgate_kernel<<<2048, 256, 0, stream>>>(obp + (size_t)b * TB * 2048, gateb, bg2, norm_w, ogb);
            gemm_bf16<float><<<dim3(16, TB / 128), 256, 0, stream>>>(ogb, wob,
                (float*)d_out + (size_t)b * TB * 2048, TB, 2048, 2048);
        }
    } else {
        for (int b = 0; b < 2; ++b) {
            const float* xbp = x + (size_t)b * TB * 2048;
            float* outp = (float*)d_out + (size_t)b * TB * 2048;
            cast_f32_bf16<<<512, 256, 0, stream>>>(xbp, xb, TB * 2048);
            gemm_bf16<ushort><<<dim3(48, TB / 128), 256, 0, stream>>>(xb, wqkv, qkvb, TB, 6144, 2048);
            conv_stats_kernel<<<TB * 16 / 8, 256, 0, stream>>>(qkvb, convq, convk, convv, Wsv,
                Wb1, bb1, Wb2, bb2, Wa1, ba1, Wa2, ba2, A_log, dt_bias, P);
            gemm_bf16<ushort><<<dim3(1, TB / 128), 256, 0, stream>>>(xb, wg1b, xg1b, TB, 128, 2048);
            gemm_bf16<ushort><<<dim3(16, TB / 128), 256, 0, stream>>>(xg1b, wg2b, gateb, TB, 2048, 128);
            cast_f32_bf16<<<512, 256, 0, stream>>>(Wo, wob, 4194304);
            prepass_kernel<<<16 * 1024, 256, 0, stream>>>(P);
            scan_kernel<<<128, 256, 0, stream>>>(P, xb, 15, 4);   // xb dead -> ob
            normgate_kernel<<<2048, 256, 0, stream>>>(xb, gateb, bg2, norm_w, ogb);
            gemm_bf16<float><<<dim3(16, TB / 128), 256, 0, stream>>>(ogb, wob, outp, TB, 2048, 2048);
        }
    }
}